// Round 1
// 1729.750 us; speedup vs baseline: 1.3658x; 1.3658x over previous
//
#include <hip/hip_runtime.h>

// Problem constants
#define BB 2
#define SS 2048
#define DD 1024
#define HH 16
#define DHH 64
#define NN (BB*SS)   // 4096

// ---------------- GEMM: C[n,j] = sum_d A[n,d]*W[j,d] + bias[j] ----------------
// A: (NN, DD) row-major. W: (DD, DD) row-major (torch Linear weight).
// mode 0: plain store to out[n*DD + j]
// mode 1: head-split store to out[((b*HH+h)*SS + s)*DHH + dh], j = h*DHH+dh
// 128x64 tile, 256 threads, 8x4 per-thread register tile (FMA:ds_read = 32:3).
#define BM 128
#define BN 64
#define BK 16

__global__ __launch_bounds__(256) void gemm_nt_bias(
    const float* __restrict__ A, const float* __restrict__ W,
    const float* __restrict__ bias, float* __restrict__ out, int mode) {
  __shared__ __align__(16) float As[BK][BM + 4];  // transposed: As[k][m], stride 132 (16B-aligned rows)
  __shared__ __align__(16) float Bs[BK][BN + 4];  // Bs[k][j], stride 68
  const int t  = threadIdx.x;
  const int tx = t & 15, ty = t >> 4;
  const int m0 = blockIdx.y * BM;
  const int n0 = blockIdx.x * BN;

  float acc[8][4] = {};

  for (int k0 = 0; k0 < DD; k0 += BK) {
    // stage A tile (128x16) transposed: 512 float4, 2 per thread
#pragma unroll
    for (int r = 0; r < 2; ++r) {
      int idx = t + 256 * r;
      int kq = idx & 3, m = idx >> 2;       // m 0..127, kq 0..3
      float4 av = *(const float4*)&A[(size_t)(m0 + m) * DD + k0 + kq * 4];
      As[kq*4+0][m] = av.x; As[kq*4+1][m] = av.y;
      As[kq*4+2][m] = av.z; As[kq*4+3][m] = av.w;
    }
    // stage B tile (64x16) transposed: 256 float4, 1 per thread
    {
      int kq = t & 3, n = t >> 2;           // n 0..63
      float4 bv = *(const float4*)&W[(size_t)(n0 + n) * DD + k0 + kq * 4];
      Bs[kq*4+0][n] = bv.x; Bs[kq*4+1][n] = bv.y;
      Bs[kq*4+2][n] = bv.z; Bs[kq*4+3][n] = bv.w;
    }
    __syncthreads();
#pragma unroll
    for (int kk = 0; kk < BK; ++kk) {
      float4 a0 = *(const float4*)&As[kk][ty * 8];
      float4 a1 = *(const float4*)&As[kk][ty * 8 + 4];
      float4 bv = *(const float4*)&Bs[kk][tx * 4];
      float aa[8] = {a0.x, a0.y, a0.z, a0.w, a1.x, a1.y, a1.z, a1.w};
      float bb[4] = {bv.x, bv.y, bv.z, bv.w};
#pragma unroll
      for (int im = 0; im < 8; ++im)
#pragma unroll
        for (int in = 0; in < 4; ++in)
          acc[im][in] += aa[im] * bb[in];
    }
    __syncthreads();
  }

  const int jbase = n0 + tx * 4;
  float4 bvec = *(const float4*)&bias[jbase];
  float barr[4] = {bvec.x, bvec.y, bvec.z, bvec.w};
#pragma unroll
  for (int im = 0; im < 8; ++im) {
    int n = m0 + ty * 8 + im;
    float4 res;
    res.x = acc[im][0] + barr[0];
    res.y = acc[im][1] + barr[1];
    res.z = acc[im][2] + barr[2];
    res.w = acc[im][3] + barr[3];
    if (mode == 0) {
      *(float4*)&out[(size_t)n * DD + jbase] = res;
    } else {
      int b = n >> 11, s = n & (SS - 1);
      int h = jbase >> 6, dh = jbase & 63;
      *(float4*)&out[(((size_t)(b * HH + h) * SS) + s) * DHH + dh] = res;
    }
  }
}

// ---------------- Attention ----------------
// q,k,v in (B,H,S,Dh) fp32. One block per (bh, 128-row q tile). 256 threads.
// Thread (ty=t>>4, tx=t&15) owns rows ty*8..+7, cols tx*4..+3 of each
// 128x64 score tile (8x4 register tile -> 32 FMA per 3 ds_read_b128).
// Phase 1: stream K tiles, recompute-free online (m,l) entirely in registers
//          (shfl_xor reductions across the 16-lane tx group; no LDS, no
//          serial sections, no extra barriers).
// Phase 2: re-stage K, recompute scores, p = exp(s-m)*invl, write p once to
//          attn_g (the only score traffic to HBM), transpose p into LDS,
//          accumulate PV into registers, write out_head (B,S,D).
#define RB 128
#define CT 64

__global__ __launch_bounds__(256) void attn_kernel(
    const float* __restrict__ q, const float* __restrict__ k,
    const float* __restrict__ v, const int* __restrict__ mask,
    float* __restrict__ attn_g, float* __restrict__ out_head) {
  const int bh = blockIdx.x;            // 0..31
  const int it = blockIdx.y;            // 0..15
  const int b  = bh >> 4;
  const int h  = bh & 15;
  const int i0 = it * RB;

  // 80 KB total -> 2 blocks/CU. stride 128 floats = 512 B (16B-aligned rows).
  __shared__ __align__(16) float qT[64][RB];   // qT[d][r]
  __shared__ __align__(16) float kps[64][RB];  // K^T[d][j] (cols<64) OR psT[j][r]
  __shared__ __align__(16) float vs[CT][64];   // vs[j][d]

  const int t  = threadIdx.x;
  const int tx = t & 15;
  const int ty = t >> 4;

  // ---- stage Q tile transposed (once). d4=4*ty slab, rows via tx. ----
  {
    int d4 = ty * 4;
#pragma unroll
    for (int rr = 0; rr < 8; ++rr) {
      int row = tx + 16 * rr;
      float4 qv = *(const float4*)&q[((size_t)bh * SS + i0 + row) * DHH + d4];
      qT[d4+0][row] = qv.x; qT[d4+1][row] = qv.y;
      qT[d4+2][row] = qv.z; qT[d4+3][row] = qv.w;
    }
  }

  float m[8], l[8];
#pragma unroll
  for (int qq = 0; qq < 8; ++qq) { m[qq] = -1e30f; l[qq] = 0.0f; }

  const float scale = 0.125f;  // 1/sqrt(64)

  // ---------- phase 1: online (m,l), no global score traffic ----------
  for (int jt = 0; jt < SS / CT; ++jt) {
    int j0 = jt * CT;
    {
      int d4 = ty * 4;
#pragma unroll
      for (int rr = 0; rr < 4; ++rr) {
        int row = tx + 16 * rr;
        float4 kv = *(const float4*)&k[((size_t)bh * SS + j0 + row) * DHH + d4];
        kps[d4+0][row] = kv.x; kps[d4+1][row] = kv.y;
        kps[d4+2][row] = kv.z; kps[d4+3][row] = kv.w;
      }
    }
    __syncthreads();

    float sc[8][4] = {};
#pragma unroll 4
    for (int d = 0; d < 64; ++d) {
      float4 a0 = *(const float4*)&qT[d][ty * 8];
      float4 a1 = *(const float4*)&qT[d][ty * 8 + 4];
      float4 kb = *(const float4*)&kps[d][tx * 4];
      float aa[8] = {a0.x, a0.y, a0.z, a0.w, a1.x, a1.y, a1.z, a1.w};
      float bb[4] = {kb.x, kb.y, kb.z, kb.w};
#pragma unroll
      for (int qq = 0; qq < 8; ++qq)
#pragma unroll
        for (int c = 0; c < 4; ++c)
          sc[qq][c] += aa[qq] * bb[c];
    }
    int4 mv = *(const int4*)&mask[b * SS + j0 + tx * 4];
    int mm[4] = {mv.x, mv.y, mv.z, mv.w};
#pragma unroll
    for (int qq = 0; qq < 8; ++qq)
#pragma unroll
      for (int c = 0; c < 4; ++c) {
        float s = sc[qq][c] * scale;
        sc[qq][c] = (mm[c] == 0) ? -1e9f : s;
      }
    // register-only online softmax state update
#pragma unroll
    for (int qq = 0; qq < 8; ++qq) {
      float tm = fmaxf(fmaxf(sc[qq][0], sc[qq][1]), fmaxf(sc[qq][2], sc[qq][3]));
      tm = fmaxf(tm, __shfl_xor(tm, 1));
      tm = fmaxf(tm, __shfl_xor(tm, 2));
      tm = fmaxf(tm, __shfl_xor(tm, 4));
      tm = fmaxf(tm, __shfl_xor(tm, 8));
      float nm = fmaxf(m[qq], tm);
      float ps = __expf(sc[qq][0] - nm) + __expf(sc[qq][1] - nm) +
                 __expf(sc[qq][2] - nm) + __expf(sc[qq][3] - nm);
      ps += __shfl_xor(ps, 1);
      ps += __shfl_xor(ps, 2);
      ps += __shfl_xor(ps, 4);
      ps += __shfl_xor(ps, 8);
      l[qq] = l[qq] * __expf(m[qq] - nm) + ps;
      m[qq] = nm;
    }
    __syncthreads();
  }

  float invl[8];
#pragma unroll
  for (int qq = 0; qq < 8; ++qq) invl[qq] = 1.0f / l[qq];

  // ---------- phase 2: recompute scores, write p once, PV ----------
  float acc[8][4] = {};
  for (int jt = 0; jt < SS / CT; ++jt) {
    int j0 = jt * CT;
    {
      int d4 = ty * 4;
#pragma unroll
      for (int rr = 0; rr < 4; ++rr) {
        int row = tx + 16 * rr;
        float4 kv = *(const float4*)&k[((size_t)bh * SS + j0 + row) * DHH + d4];
        kps[d4+0][row] = kv.x; kps[d4+1][row] = kv.y;
        kps[d4+2][row] = kv.z; kps[d4+3][row] = kv.w;
      }
#pragma unroll
      for (int rr = 0; rr < 4; ++rr) {
        int row = ty + 16 * rr;
        *(float4*)&vs[row][tx * 4] =
            *(const float4*)&v[((size_t)bh * SS + j0 + row) * DHH + tx * 4];
      }
    }
    __syncthreads();

    float sc[8][4] = {};
#pragma unroll 4
    for (int d = 0; d < 64; ++d) {
      float4 a0 = *(const float4*)&qT[d][ty * 8];
      float4 a1 = *(const float4*)&qT[d][ty * 8 + 4];
      float4 kb = *(const float4*)&kps[d][tx * 4];
      float aa[8] = {a0.x, a0.y, a0.z, a0.w, a1.x, a1.y, a1.z, a1.w};
      float bb[4] = {kb.x, kb.y, kb.z, kb.w};
#pragma unroll
      for (int qq = 0; qq < 8; ++qq)
#pragma unroll
        for (int c = 0; c < 4; ++c)
          sc[qq][c] += aa[qq] * bb[c];
    }
    int4 mv = *(const int4*)&mask[b * SS + j0 + tx * 4];
    int mm[4] = {mv.x, mv.y, mv.z, mv.w};
    // p = exp(s-m)/l, in place over sc
#pragma unroll
    for (int qq = 0; qq < 8; ++qq)
#pragma unroll
      for (int c = 0; c < 4; ++c) {
        float s = sc[qq][c] * scale;
        s = (mm[c] == 0) ? -1e9f : s;
        sc[qq][c] = __expf(s - m[qq]) * invl[qq];
      }
    // final attn values -> global (only score write to HBM), coalesced
    {
      float* arow = attn_g + ((size_t)bh * SS + i0) * SS + j0;
#pragma unroll
      for (int qq = 0; qq < 8; ++qq) {
        float4 w = make_float4(sc[qq][0], sc[qq][1], sc[qq][2], sc[qq][3]);
        *(float4*)&arow[(size_t)(ty * 8 + qq) * SS + tx * 4] = w;
      }
    }
    __syncthreads();  // everyone done reading kps as K^T
    // transpose p into kps as psT[j][r]
#pragma unroll
    for (int c = 0; c < 4; ++c) {
      float4 w0 = make_float4(sc[0][c], sc[1][c], sc[2][c], sc[3][c]);
      float4 w1 = make_float4(sc[4][c], sc[5][c], sc[6][c], sc[7][c]);
      *(float4*)&kps[tx * 4 + c][ty * 8]     = w0;
      *(float4*)&kps[tx * 4 + c][ty * 8 + 4] = w1;
    }
    __syncthreads();
    // PV: acc[r][d] += p[r][j] * v[j][d]
#pragma unroll 4
    for (int j = 0; j < CT; ++j) {
      float4 pa = *(const float4*)&kps[j][ty * 8];
      float4 pb = *(const float4*)&kps[j][ty * 8 + 4];
      float4 vv = *(const float4*)&vs[j][tx * 4];
      float pp[8] = {pa.x, pa.y, pa.z, pa.w, pb.x, pb.y, pb.z, pb.w};
#pragma unroll
      for (int qq = 0; qq < 8; ++qq) {
        acc[qq][0] += pp[qq] * vv.x;
        acc[qq][1] += pp[qq] * vv.y;
        acc[qq][2] += pp[qq] * vv.z;
        acc[qq][3] += pp[qq] * vv.w;
      }
    }
    __syncthreads();
  }

  // out_head plain (B,S,D): rows i0+ty*8+qq, cols h*64 + tx*4
#pragma unroll
  for (int qq = 0; qq < 8; ++qq) {
    float4 res = make_float4(acc[qq][0], acc[qq][1], acc[qq][2], acc[qq][3]);
    *(float4*)&out_head[((size_t)b * SS + i0 + ty * 8 + qq) * DD + h * DHH + tx * 4] = res;
  }
}

// ---------------- launch ----------------
extern "C" void kernel_launch(void* const* d_in, const int* in_sizes, int n_in,
                              void* d_out, int out_size, void* d_ws, size_t ws_size,
                              hipStream_t stream) {
  const float* Q   = (const float*)d_in[0];
  const float* K   = (const float*)d_in[1];
  const float* V   = (const float*)d_in[2];
  const int*  mask = (const int*)d_in[3];
  const float* Wq  = (const float*)d_in[4];
  const float* bq  = (const float*)d_in[5];
  const float* Wk  = (const float*)d_in[6];
  const float* bk  = (const float*)d_in[7];
  const float* Wv  = (const float*)d_in[8];
  const float* bv  = (const float*)d_in[9];
  const float* Wo  = (const float*)d_in[10];
  const float* bo  = (const float*)d_in[11];

  float* out    = (float*)d_out;                       // (B,S,D)
  float* attn_g = out + (size_t)NN * DD;               // (B,H,S,S)

  float* ws = (float*)d_ws;
  float* qh = ws;                                      // (B,H,S,Dh)
  float* kh = qh + (size_t)NN * DD;
  float* vh = kh + (size_t)NN * DD;
  float* oh = vh + (size_t)NN * DD;                    // (B,S,D)

  dim3 gGemm(DD / BN, NN / BM);   // (16, 32)
  dim3 bGemm(256);

  hipLaunchKernelGGL(gemm_nt_bias, gGemm, bGemm, 0, stream, Q, Wq, bq, qh, 1);
  hipLaunchKernelGGL(gemm_nt_bias, gGemm, bGemm, 0, stream, K, Wk, bk, kh, 1);
  hipLaunchKernelGGL(gemm_nt_bias, gGemm, bGemm, 0, stream, V, Wv, bv, vh, 1);

  dim3 gAttn(BB * HH, SS / RB);   // (32, 16)
  hipLaunchKernelGGL(attn_kernel, gAttn, dim3(256), 0, stream,
                     qh, kh, vh, mask, attn_g, oh);

  hipLaunchKernelGGL(gemm_nt_bias, gGemm, bGemm, 0, stream, oh, Wo, bo, out, 0);
}

// Round 2
// 1672.887 us; speedup vs baseline: 1.4122x; 1.0340x over previous
//
#include <hip/hip_runtime.h>

// Problem constants
#define BB 2
#define SS 2048
#define DD 1024
#define HH 16
#define DHH 64
#define NN (BB*SS)   // 4096

typedef __attribute__((ext_vector_type(8))) __bf16 bf16x8;
typedef __attribute__((ext_vector_type(4))) float f32x4;

__device__ __forceinline__ unsigned short f2bf(float f) {
  unsigned int u = __float_as_uint(f);
  return (unsigned short)((u + 0x7FFFu + ((u >> 16) & 1u)) >> 16);
}

// ---------------- split: fp32 -> (hi, lo) bf16 planes ----------------
// hi = rne_bf16(x); lo = rne_bf16(x - hi).  x ~= hi + lo to ~2^-16 rel.
__global__ __launch_bounds__(256) void split_hl(
    const float* __restrict__ x, unsigned short* __restrict__ hi,
    unsigned short* __restrict__ lo, int n4) {
  int i = blockIdx.x * 256 + threadIdx.x;
  int stride = gridDim.x * 256;
  for (; i < n4; i += stride) {
    float4 v = ((const float4*)x)[i];
    float f[4] = {v.x, v.y, v.z, v.w};
    unsigned short hs[4], ls[4];
#pragma unroll
    for (int j = 0; j < 4; ++j) {
      hs[j] = f2bf(f[j]);
      float r = f[j] - __uint_as_float(((unsigned int)hs[j]) << 16);
      ls[j] = f2bf(r);
    }
    ushort4 H, L;
    H.x = hs[0]; H.y = hs[1]; H.z = hs[2]; H.w = hs[3];
    L.x = ls[0]; L.y = ls[1]; L.z = ls[2]; L.w = ls[3];
    ((ushort4*)hi)[i] = H;
    ((ushort4*)lo)[i] = L;
  }
}

// ---------------- GEMM (bf16x3 MFMA): C[m,n] = sum_k A[m,k]*W[n,k] + bias[n] --
// A,W given as hi/lo bf16 planes, row-major [rows][1024].
// mode 0: out[m*DD + n]; mode 1: head-split store.
// 128x128 tile, BK=64, 256 thr = 4 waves (2x2), wave tile 64x64 = 4x4 frags
// of 16x16x32.  LDS XOR-swizzled (ks ^ (row&7)) -> conflict-free ds_read_b128.
#define GBM 128
#define GBN 128
#define GBK 64

__global__ __launch_bounds__(256, 1) void gemm_bf16x3(
    const unsigned short* __restrict__ Ah, const unsigned short* __restrict__ Al,
    const unsigned short* __restrict__ Bh, const unsigned short* __restrict__ Bl,
    const float* __restrict__ bias, float* __restrict__ out, int mode) {
  __shared__ __align__(16) unsigned short sAh[GBM * GBK];
  __shared__ __align__(16) unsigned short sAl[GBM * GBK];
  __shared__ __align__(16) unsigned short sBh[GBN * GBK];
  __shared__ __align__(16) unsigned short sBl[GBN * GBK];

  const int t  = threadIdx.x;
  const int l  = t & 63;
  const int w  = t >> 6;
  const int wr = w >> 1, wc = w & 1;
  const int m0 = blockIdx.y * GBM, n0 = blockIdx.x * GBN;

  f32x4 acc[4][4] = {};

  // staging: slot s = r*256 + t; row = s>>3 (= r*32 + (t>>3)), kq = t&7
  const int srow = t >> 3;
  const int skq  = t & 7;
  uint4 pr[16];

  auto LOAD = [&](int k0) {
#pragma unroll
    for (int r = 0; r < 4; ++r) {
      size_t offA = (size_t)(m0 + r * 32 + srow) * DD + k0 + skq * 8;
      size_t offB = (size_t)(n0 + r * 32 + srow) * DD + k0 + skq * 8;
      pr[r]      = *(const uint4*)&Ah[offA];
      pr[4 + r]  = *(const uint4*)&Al[offA];
      pr[8 + r]  = *(const uint4*)&Bh[offB];
      pr[12 + r] = *(const uint4*)&Bl[offB];
    }
  };
  auto STORE = [&]() {
#pragma unroll
    for (int r = 0; r < 4; ++r) {
      int wb = ((r * 256 + t) * 16) ^ ((srow & 7) << 4);
      *(uint4*)((char*)sAh + wb) = pr[r];
      *(uint4*)((char*)sAl + wb) = pr[4 + r];
      *(uint4*)((char*)sBh + wb) = pr[8 + r];
      *(uint4*)((char*)sBl + wb) = pr[12 + r];
    }
  };
  auto COMPUTE = [&]() {
#pragma unroll
    for (int kk = 0; kk < 2; ++kk) {
      bf16x8 ah[4], al[4], bh[4], bl[4];
      const int ks = kk * 4 + (l >> 4);
      const int sw = (ks ^ (l & 7)) << 4;   // row&7 == l&7 for all frag rows
#pragma unroll
      for (int f = 0; f < 4; ++f) {
        int ra = (wr * 64 + f * 16 + (l & 15)) * 128 + sw;
        int rb = (wc * 64 + f * 16 + (l & 15)) * 128 + sw;
        ah[f] = *(const bf16x8*)((const char*)sAh + ra);
        al[f] = *(const bf16x8*)((const char*)sAl + ra);
        bh[f] = *(const bf16x8*)((const char*)sBh + rb);
        bl[f] = *(const bf16x8*)((const char*)sBl + rb);
      }
#pragma unroll
      for (int fm = 0; fm < 4; ++fm)
#pragma unroll
        for (int fn = 0; fn < 4; ++fn) {
          acc[fm][fn] = __builtin_amdgcn_mfma_f32_16x16x32_bf16(ah[fm], bh[fn], acc[fm][fn], 0, 0, 0);
          acc[fm][fn] = __builtin_amdgcn_mfma_f32_16x16x32_bf16(ah[fm], bl[fn], acc[fm][fn], 0, 0, 0);
          acc[fm][fn] = __builtin_amdgcn_mfma_f32_16x16x32_bf16(al[fm], bh[fn], acc[fm][fn], 0, 0, 0);
        }
    }
  };

  LOAD(0);
  STORE();
  __syncthreads();
  const int NT = DD / GBK;  // 16
  for (int kt = 0; kt < NT; ++kt) {
    if (kt + 1 < NT) LOAD((kt + 1) * GBK);  // prefetch next tile into regs
    COMPUTE();
    __syncthreads();
    if (kt + 1 < NT) { STORE(); __syncthreads(); }
  }

  // epilogue: C/D layout col = lane&15, row = (lane>>4)*4 + reg  [verified]
#pragma unroll
  for (int fn = 0; fn < 4; ++fn) {
    int col = n0 + wc * 64 + fn * 16 + (l & 15);
    float bv = bias[col];
#pragma unroll
    for (int fm = 0; fm < 4; ++fm) {
      int rbase = m0 + wr * 64 + fm * 16 + (l >> 4) * 4;
#pragma unroll
      for (int r = 0; r < 4; ++r) {
        int row = rbase + r;
        float val = acc[fm][fn][r] + bv;
        if (mode == 0) {
          out[(size_t)row * DD + col] = val;
        } else {
          int b = row >> 11, s2 = row & (SS - 1);
          int h = col >> 6, dh = col & 63;
          out[(((size_t)(b * HH + h) * SS) + s2) * DHH + dh] = val;
        }
      }
    }
  }
}

// ---------------- Attention (unchanged structure from round 1) ----------------
// Epilogue change only: emit hi/lo bf16 planes of the head-merged output
// directly (the fp32 oh array is never materialized).
#define RB 128
#define CT 64

__global__ __launch_bounds__(256) void attn_kernel(
    const float* __restrict__ q, const float* __restrict__ k,
    const float* __restrict__ v, const int* __restrict__ mask,
    float* __restrict__ attn_g, unsigned short* __restrict__ hiO,
    unsigned short* __restrict__ loO) {
  const int bh = blockIdx.x;            // 0..31
  const int it = blockIdx.y;            // 0..15
  const int b  = bh >> 4;
  const int h  = bh & 15;
  const int i0 = it * RB;

  __shared__ __align__(16) float qT[64][RB];   // qT[d][r]
  __shared__ __align__(16) float kps[64][RB];  // K^T[d][j] OR psT[j][r]
  __shared__ __align__(16) float vs[CT][64];   // vs[j][d]

  const int t  = threadIdx.x;
  const int tx = t & 15;
  const int ty = t >> 4;

  {
    int d4 = ty * 4;
#pragma unroll
    for (int rr = 0; rr < 8; ++rr) {
      int row = tx + 16 * rr;
      float4 qv = *(const float4*)&q[((size_t)bh * SS + i0 + row) * DHH + d4];
      qT[d4+0][row] = qv.x; qT[d4+1][row] = qv.y;
      qT[d4+2][row] = qv.z; qT[d4+3][row] = qv.w;
    }
  }

  float m[8], lsum[8];
#pragma unroll
  for (int qq = 0; qq < 8; ++qq) { m[qq] = -1e30f; lsum[qq] = 0.0f; }

  const float scale = 0.125f;  // 1/sqrt(64)

  // ---------- phase 1: online (m,l) ----------
  for (int jt = 0; jt < SS / CT; ++jt) {
    int j0 = jt * CT;
    {
      int d4 = ty * 4;
#pragma unroll
      for (int rr = 0; rr < 4; ++rr) {
        int row = tx + 16 * rr;
        float4 kv = *(const float4*)&k[((size_t)bh * SS + j0 + row) * DHH + d4];
        kps[d4+0][row] = kv.x; kps[d4+1][row] = kv.y;
        kps[d4+2][row] = kv.z; kps[d4+3][row] = kv.w;
      }
    }
    __syncthreads();

    float sc[8][4] = {};
#pragma unroll 4
    for (int d = 0; d < 64; ++d) {
      float4 a0 = *(const float4*)&qT[d][ty * 8];
      float4 a1 = *(const float4*)&qT[d][ty * 8 + 4];
      float4 kb = *(const float4*)&kps[d][tx * 4];
      float aa[8] = {a0.x, a0.y, a0.z, a0.w, a1.x, a1.y, a1.z, a1.w};
      float bb[4] = {kb.x, kb.y, kb.z, kb.w};
#pragma unroll
      for (int qq = 0; qq < 8; ++qq)
#pragma unroll
        for (int c = 0; c < 4; ++c)
          sc[qq][c] += aa[qq] * bb[c];
    }
    int4 mv = *(const int4*)&mask[b * SS + j0 + tx * 4];
    int mm[4] = {mv.x, mv.y, mv.z, mv.w};
#pragma unroll
    for (int qq = 0; qq < 8; ++qq)
#pragma unroll
      for (int c = 0; c < 4; ++c) {
        float s = sc[qq][c] * scale;
        sc[qq][c] = (mm[c] == 0) ? -1e9f : s;
      }
#pragma unroll
    for (int qq = 0; qq < 8; ++qq) {
      float tm = fmaxf(fmaxf(sc[qq][0], sc[qq][1]), fmaxf(sc[qq][2], sc[qq][3]));
      tm = fmaxf(tm, __shfl_xor(tm, 1));
      tm = fmaxf(tm, __shfl_xor(tm, 2));
      tm = fmaxf(tm, __shfl_xor(tm, 4));
      tm = fmaxf(tm, __shfl_xor(tm, 8));
      float nm = fmaxf(m[qq], tm);
      float ps = __expf(sc[qq][0] - nm) + __expf(sc[qq][1] - nm) +
                 __expf(sc[qq][2] - nm) + __expf(sc[qq][3] - nm);
      ps += __shfl_xor(ps, 1);
      ps += __shfl_xor(ps, 2);
      ps += __shfl_xor(ps, 4);
      ps += __shfl_xor(ps, 8);
      lsum[qq] = lsum[qq] * __expf(m[qq] - nm) + ps;
      m[qq] = nm;
    }
    __syncthreads();
  }

  float invl[8];
#pragma unroll
  for (int qq = 0; qq < 8; ++qq) invl[qq] = 1.0f / lsum[qq];

  // ---------- phase 2: recompute scores, write p once, PV ----------
  float acc[8][4] = {};
  for (int jt = 0; jt < SS / CT; ++jt) {
    int j0 = jt * CT;
    {
      int d4 = ty * 4;
#pragma unroll
      for (int rr = 0; rr < 4; ++rr) {
        int row = tx + 16 * rr;
        float4 kv = *(const float4*)&k[((size_t)bh * SS + j0 + row) * DHH + d4];
        kps[d4+0][row] = kv.x; kps[d4+1][row] = kv.y;
        kps[d4+2][row] = kv.z; kps[d4+3][row] = kv.w;
      }
#pragma unroll
      for (int rr = 0; rr < 4; ++rr) {
        int row = ty + 16 * rr;
        *(float4*)&vs[row][tx * 4] =
            *(const float4*)&v[((size_t)bh * SS + j0 + row) * DHH + tx * 4];
      }
    }
    __syncthreads();

    float sc[8][4] = {};
#pragma unroll 4
    for (int d = 0; d < 64; ++d) {
      float4 a0 = *(const float4*)&qT[d][ty * 8];
      float4 a1 = *(const float4*)&qT[d][ty * 8 + 4];
      float4 kb = *(const float4*)&kps[d][tx * 4];
      float aa[8] = {a0.x, a0.y, a0.z, a0.w, a1.x, a1.y, a1.z, a1.w};
      float bb[4] = {kb.x, kb.y, kb.z, kb.w};
#pragma unroll
      for (int qq = 0; qq < 8; ++qq)
#pragma unroll
        for (int c = 0; c < 4; ++c)
          sc[qq][c] += aa[qq] * bb[c];
    }
    int4 mv = *(const int4*)&mask[b * SS + j0 + tx * 4];
    int mm[4] = {mv.x, mv.y, mv.z, mv.w};
#pragma unroll
    for (int qq = 0; qq < 8; ++qq)
#pragma unroll
      for (int c = 0; c < 4; ++c) {
        float s = sc[qq][c] * scale;
        s = (mm[c] == 0) ? -1e9f : s;
        sc[qq][c] = __expf(s - m[qq]) * invl[qq];
      }
    {
      float* arow = attn_g + ((size_t)bh * SS + i0) * SS + j0;
#pragma unroll
      for (int qq = 0; qq < 8; ++qq) {
        float4 wv = make_float4(sc[qq][0], sc[qq][1], sc[qq][2], sc[qq][3]);
        *(float4*)&arow[(size_t)(ty * 8 + qq) * SS + tx * 4] = wv;
      }
    }
    __syncthreads();
#pragma unroll
    for (int c = 0; c < 4; ++c) {
      float4 w0 = make_float4(sc[0][c], sc[1][c], sc[2][c], sc[3][c]);
      float4 w1 = make_float4(sc[4][c], sc[5][c], sc[6][c], sc[7][c]);
      *(float4*)&kps[tx * 4 + c][ty * 8]     = w0;
      *(float4*)&kps[tx * 4 + c][ty * 8 + 4] = w1;
    }
    __syncthreads();
#pragma unroll 4
    for (int j = 0; j < CT; ++j) {
      float4 pa = *(const float4*)&kps[j][ty * 8];
      float4 pb = *(const float4*)&kps[j][ty * 8 + 4];
      float4 vv = *(const float4*)&vs[j][tx * 4];
      float pp[8] = {pa.x, pa.y, pa.z, pa.w, pb.x, pb.y, pb.z, pb.w};
#pragma unroll
      for (int qq = 0; qq < 8; ++qq) {
        acc[qq][0] += pp[qq] * vv.x;
        acc[qq][1] += pp[qq] * vv.y;
        acc[qq][2] += pp[qq] * vv.z;
        acc[qq][3] += pp[qq] * vv.w;
      }
    }
    __syncthreads();
  }

  // epilogue: emit hi/lo bf16 planes of head-merged output (B,S,D)
#pragma unroll
  for (int qq = 0; qq < 8; ++qq) {
    size_t base = ((size_t)b * SS + i0 + ty * 8 + qq) * DD + h * DHH + tx * 4;
    unsigned short hs[4], ls[4];
#pragma unroll
    for (int j = 0; j < 4; ++j) {
      float f = acc[qq][j];
      hs[j] = f2bf(f);
      ls[j] = f2bf(f - __uint_as_float(((unsigned int)hs[j]) << 16));
    }
    ushort4 H, L;
    H.x = hs[0]; H.y = hs[1]; H.z = hs[2]; H.w = hs[3];
    L.x = ls[0]; L.y = ls[1]; L.z = ls[2]; L.w = ls[3];
    *(ushort4*)&hiO[base] = H;
    *(ushort4*)&loO[base] = L;
  }
}

// ---------------- launch ----------------
extern "C" void kernel_launch(void* const* d_in, const int* in_sizes, int n_in,
                              void* d_out, int out_size, void* d_ws, size_t ws_size,
                              hipStream_t stream) {
  const float* Q   = (const float*)d_in[0];
  const float* K   = (const float*)d_in[1];
  const float* V   = (const float*)d_in[2];
  const int*  mask = (const int*)d_in[3];
  const float* Wq  = (const float*)d_in[4];
  const float* bq  = (const float*)d_in[5];
  const float* Wk  = (const float*)d_in[6];
  const float* bk  = (const float*)d_in[7];
  const float* Wv  = (const float*)d_in[8];
  const float* bv  = (const float*)d_in[9];
  const float* Wo  = (const float*)d_in[10];
  const float* bo  = (const float*)d_in[11];

  float* out    = (float*)d_out;                       // (B,S,D)
  float* attn_g = out + (size_t)NN * DD;               // (B,H,S,S)

  // Pre-attn split planes live in attn_g (dead scratch until attn writes it).
  unsigned short* hiA = (unsigned short*)attn_g;       // NN*DD
  unsigned short* loA = hiA + (size_t)NN * DD;
  unsigned short* hiW = loA + (size_t)NN * DD;         // DD*DD
  unsigned short* loW = hiW + (size_t)DD * DD;

  float* ws = (float*)d_ws;
  float* qh = ws;                                      // (B,H,S,Dh) fp32
  float* kh = qh + (size_t)NN * DD;
  float* vh = kh + (size_t)NN * DD;
  // oh region repurposed: hi/lo bf16 planes of head-merged attn output
  unsigned short* hiO = (unsigned short*)(vh + (size_t)NN * DD);
  unsigned short* loO = hiO + (size_t)NN * DD;
  // post-attn Wo planes reuse dead qh region
  unsigned short* hiWo = (unsigned short*)qh;
  unsigned short* loWo = hiWo + (size_t)DD * DD;

  const int n4A = NN * DD / 4;   // 1048576
  const int n4W = DD * DD / 4;   // 262144

  dim3 gG(DD / GBN, NN / GBM);   // (8, 32)
  dim3 b256(256);

  // Q projection
  hipLaunchKernelGGL(split_hl, dim3(1024), b256, 0, stream, Wq, hiW, loW, n4W);
  hipLaunchKernelGGL(split_hl, dim3(2048), b256, 0, stream, Q, hiA, loA, n4A);
  hipLaunchKernelGGL(gemm_bf16x3, gG, b256, 0, stream, hiA, loA, hiW, loW, bq, qh, 1);
  // K projection
  hipLaunchKernelGGL(split_hl, dim3(1024), b256, 0, stream, Wk, hiW, loW, n4W);
  hipLaunchKernelGGL(split_hl, dim3(2048), b256, 0, stream, K, hiA, loA, n4A);
  hipLaunchKernelGGL(gemm_bf16x3, gG, b256, 0, stream, hiA, loA, hiW, loW, bk, kh, 1);
  // V projection
  hipLaunchKernelGGL(split_hl, dim3(1024), b256, 0, stream, Wv, hiW, loW, n4W);
  hipLaunchKernelGGL(split_hl, dim3(2048), b256, 0, stream, V, hiA, loA, n4A);
  hipLaunchKernelGGL(gemm_bf16x3, gG, b256, 0, stream, hiA, loA, hiW, loW, bv, vh, 1);

  // attention (overwrites attn_g scratch with the real attn output)
  dim3 gAttn(BB * HH, SS / RB);   // (32, 16)
  hipLaunchKernelGGL(attn_kernel, gAttn, b256, 0, stream,
                     qh, kh, vh, mask, attn_g, hiO, loO);

  // output projection
  hipLaunchKernelGGL(split_hl, dim3(1024), b256, 0, stream, Wo, hiWo, loWo, n4W);
  hipLaunchKernelGGL(gemm_bf16x3, gG, b256, 0, stream, hiO, loO, hiWo, loWo, bo, out, 0);
}

// Round 3
// 1429.386 us; speedup vs baseline: 1.6528x; 1.1704x over previous
//
#include <hip/hip_runtime.h>

// Problem constants
#define BB 2
#define SS 2048
#define DD 1024
#define HH 16
#define DHH 64
#define NN (BB*SS)   // 4096

typedef __attribute__((ext_vector_type(8))) __bf16 bf16x8;
typedef __attribute__((ext_vector_type(4))) float f32x4;

__device__ __forceinline__ unsigned short f2bf(float f) {
  unsigned int u = __float_as_uint(f);
  return (unsigned short)((u + 0x7FFFu + ((u >> 16) & 1u)) >> 16);
}

// global -> LDS direct (16 B per lane). LDS dest is wave-uniform base;
// HW writes base + lane*16. Global addr is per-lane (pre-swizzled source).
__device__ __forceinline__ void gl_lds16(const unsigned short* g, unsigned short* l) {
  __builtin_amdgcn_global_load_lds(
      (const __attribute__((address_space(1))) unsigned int*)g,
      (__attribute__((address_space(3))) unsigned int*)l, 16, 0, 0);
}

// ---------------- split: fp32 -> (hi, lo) bf16 planes ----------------
__global__ __launch_bounds__(256) void split_hl(
    const float* __restrict__ x, unsigned short* __restrict__ hi,
    unsigned short* __restrict__ lo, int n4) {
  int i = blockIdx.x * 256 + threadIdx.x;
  int stride = gridDim.x * 256;
  for (; i < n4; i += stride) {
    float4 v = ((const float4*)x)[i];
    float f[4] = {v.x, v.y, v.z, v.w};
    unsigned short hs[4], ls[4];
#pragma unroll
    for (int j = 0; j < 4; ++j) {
      hs[j] = f2bf(f[j]);
      float r = f[j] - __uint_as_float(((unsigned int)hs[j]) << 16);
      ls[j] = f2bf(r);
    }
    ushort4 H, L;
    H.x = hs[0]; H.y = hs[1]; H.z = hs[2]; H.w = hs[3];
    L.x = ls[0]; L.y = ls[1]; L.z = ls[2]; L.w = ls[3];
    ((ushort4*)hi)[i] = H;
    ((ushort4*)lo)[i] = L;
  }
}

// ---------------- GEMM (bf16x3 MFMA): C[m,n] = sum_k A[m,k]*W[n,k] + bias[n] --
// 128x128 tile, BK=64, 256 thr = 4 waves (2x2), wave tile 64x64 = 4x4 frags
// of 16x16x32.  Staging: global_load_lds w=16, LINEAR LDS dest; conflict-free
// ds_read via XOR swizzle realized by pre-swizzling the global SOURCE chunk
// (rule: linear dest + inverse-swz source + swz read).
#define GBM 128
#define GBN 128
#define GBK 64

__global__ __launch_bounds__(256, 2) void gemm_bf16x3(
    const unsigned short* __restrict__ Ah, const unsigned short* __restrict__ Al,
    const unsigned short* __restrict__ Bh, const unsigned short* __restrict__ Bl,
    const float* __restrict__ bias, float* __restrict__ out, int mode) {
  __shared__ __align__(16) unsigned short sAh[GBM * GBK];
  __shared__ __align__(16) unsigned short sAl[GBM * GBK];
  __shared__ __align__(16) unsigned short sBh[GBN * GBK];
  __shared__ __align__(16) unsigned short sBl[GBN * GBK];

  const int t    = threadIdx.x;
  const int l    = t & 63;
  const int w    = t >> 6;            // wave 0..3
  const int wr   = w >> 1, wc = w & 1;
  const int m0   = blockIdx.y * GBM, n0 = blockIdx.x * GBN;

  // staging geometry: one gl_lds16 stages 8 rows x 64 cols (1 KB) per wave.
  // lane i -> LDS (row base+ (i>>3), chunk i&7); source chunk pre-swizzled so
  // LDS[row][c] = global[row][c ^ (row&7)]  (row&7 == i>>3, base % 8 == 0).
  const int lrow   = l >> 3;                 // 0..7
  const int lchunk = (l & 7) ^ lrow;         // pre-swizzled source chunk

  f32x4 acc[4][4] = {};

  const int NT = DD / GBK;  // 16
  for (int kt = 0; kt < NT; ++kt) {
    const int k0 = kt * GBK;
    // ---- stage 4 planes: 4 waves x 4 iters x 8 rows = 128 rows each ----
#pragma unroll
    for (int r = 0; r < 4; ++r) {
      int rowb = w * 32 + r * 8;             // wave-uniform
      size_t gA = (size_t)(m0 + rowb + lrow) * DD + k0 + lchunk * 8;
      size_t gB = (size_t)(n0 + rowb + lrow) * DD + k0 + lchunk * 8;
      int lo = rowb * 64;                    // ushort index, wave-uniform
      gl_lds16(Ah + gA, sAh + lo);
      gl_lds16(Al + gA, sAl + lo);
      gl_lds16(Bh + gB, sBh + lo);
      gl_lds16(Bl + gB, sBl + lo);
    }
    __syncthreads();   // compiler emits vmcnt(0) drain before barrier

    // ---- compute (identical to verified round-2 inner loop) ----
#pragma unroll
    for (int kk = 0; kk < 2; ++kk) {
      bf16x8 ah[4], al[4], bh[4], bl[4];
      const int ks = kk * 4 + (l >> 4);
      const int sw = (ks ^ (l & 7)) << 4;    // row&7 == l&7 for all frag rows
#pragma unroll
      for (int f = 0; f < 4; ++f) {
        int ra = (wr * 64 + f * 16 + (l & 15)) * 128 + sw;
        int rb = (wc * 64 + f * 16 + (l & 15)) * 128 + sw;
        ah[f] = *(const bf16x8*)((const char*)sAh + ra);
        al[f] = *(const bf16x8*)((const char*)sAl + ra);
        bh[f] = *(const bf16x8*)((const char*)sBh + rb);
        bl[f] = *(const bf16x8*)((const char*)sBl + rb);
      }
#pragma unroll
      for (int fm = 0; fm < 4; ++fm)
#pragma unroll
        for (int fn = 0; fn < 4; ++fn) {
          acc[fm][fn] = __builtin_amdgcn_mfma_f32_16x16x32_bf16(ah[fm], bh[fn], acc[fm][fn], 0, 0, 0);
          acc[fm][fn] = __builtin_amdgcn_mfma_f32_16x16x32_bf16(ah[fm], bl[fn], acc[fm][fn], 0, 0, 0);
          acc[fm][fn] = __builtin_amdgcn_mfma_f32_16x16x32_bf16(al[fm], bh[fn], acc[fm][fn], 0, 0, 0);
        }
    }
    __syncthreads();   // LDS reuse next K-tile
  }

  // epilogue: C/D layout col = lane&15, row = (lane>>4)*4 + reg  [verified]
#pragma unroll
  for (int fn = 0; fn < 4; ++fn) {
    int col = n0 + wc * 64 + fn * 16 + (l & 15);
    float bv = bias[col];
#pragma unroll
    for (int fm = 0; fm < 4; ++fm) {
      int rbase = m0 + wr * 64 + fm * 16 + (l >> 4) * 4;
#pragma unroll
      for (int r = 0; r < 4; ++r) {
        int row = rbase + r;
        float val = acc[fm][fn][r] + bv;
        if (mode == 0) {
          out[(size_t)row * DD + col] = val;
        } else {
          int b = row >> 11, s2 = row & (SS - 1);
          int h = col >> 6, dh = col & 63;
          out[(((size_t)(b * HH + h) * SS) + s2) * DHH + dh] = val;
        }
      }
    }
  }
}

// ---------------- Attention (identical to round 2) ----------------
#define RB 128
#define CT 64

__global__ __launch_bounds__(256) void attn_kernel(
    const float* __restrict__ q, const float* __restrict__ k,
    const float* __restrict__ v, const int* __restrict__ mask,
    float* __restrict__ attn_g, unsigned short* __restrict__ hiO,
    unsigned short* __restrict__ loO) {
  const int bh = blockIdx.x;            // 0..31
  const int it = blockIdx.y;            // 0..15
  const int b  = bh >> 4;
  const int h  = bh & 15;
  const int i0 = it * RB;

  __shared__ __align__(16) float qT[64][RB];   // qT[d][r]
  __shared__ __align__(16) float kps[64][RB];  // K^T[d][j] OR psT[j][r]
  __shared__ __align__(16) float vs[CT][64];   // vs[j][d]

  const int t  = threadIdx.x;
  const int tx = t & 15;
  const int ty = t >> 4;

  {
    int d4 = ty * 4;
#pragma unroll
    for (int rr = 0; rr < 8; ++rr) {
      int row = tx + 16 * rr;
      float4 qv = *(const float4*)&q[((size_t)bh * SS + i0 + row) * DHH + d4];
      qT[d4+0][row] = qv.x; qT[d4+1][row] = qv.y;
      qT[d4+2][row] = qv.z; qT[d4+3][row] = qv.w;
    }
  }

  float m[8], lsum[8];
#pragma unroll
  for (int qq = 0; qq < 8; ++qq) { m[qq] = -1e30f; lsum[qq] = 0.0f; }

  const float scale = 0.125f;  // 1/sqrt(64)

  // ---------- phase 1: online (m,l) ----------
  for (int jt = 0; jt < SS / CT; ++jt) {
    int j0 = jt * CT;
    {
      int d4 = ty * 4;
#pragma unroll
      for (int rr = 0; rr < 4; ++rr) {
        int row = tx + 16 * rr;
        float4 kv = *(const float4*)&k[((size_t)bh * SS + j0 + row) * DHH + d4];
        kps[d4+0][row] = kv.x; kps[d4+1][row] = kv.y;
        kps[d4+2][row] = kv.z; kps[d4+3][row] = kv.w;
      }
    }
    __syncthreads();

    float sc[8][4] = {};
#pragma unroll 4
    for (int d = 0; d < 64; ++d) {
      float4 a0 = *(const float4*)&qT[d][ty * 8];
      float4 a1 = *(const float4*)&qT[d][ty * 8 + 4];
      float4 kb = *(const float4*)&kps[d][tx * 4];
      float aa[8] = {a0.x, a0.y, a0.z, a0.w, a1.x, a1.y, a1.z, a1.w};
      float bb[4] = {kb.x, kb.y, kb.z, kb.w};
#pragma unroll
      for (int qq = 0; qq < 8; ++qq)
#pragma unroll
        for (int c = 0; c < 4; ++c)
          sc[qq][c] += aa[qq] * bb[c];
    }
    int4 mv = *(const int4*)&mask[b * SS + j0 + tx * 4];
    int mm[4] = {mv.x, mv.y, mv.z, mv.w};
#pragma unroll
    for (int qq = 0; qq < 8; ++qq)
#pragma unroll
      for (int c = 0; c < 4; ++c) {
        float s = sc[qq][c] * scale;
        sc[qq][c] = (mm[c] == 0) ? -1e9f : s;
      }
#pragma unroll
    for (int qq = 0; qq < 8; ++qq) {
      float tm = fmaxf(fmaxf(sc[qq][0], sc[qq][1]), fmaxf(sc[qq][2], sc[qq][3]));
      tm = fmaxf(tm, __shfl_xor(tm, 1));
      tm = fmaxf(tm, __shfl_xor(tm, 2));
      tm = fmaxf(tm, __shfl_xor(tm, 4));
      tm = fmaxf(tm, __shfl_xor(tm, 8));
      float nm = fmaxf(m[qq], tm);
      float ps = __expf(sc[qq][0] - nm) + __expf(sc[qq][1] - nm) +
                 __expf(sc[qq][2] - nm) + __expf(sc[qq][3] - nm);
      ps += __shfl_xor(ps, 1);
      ps += __shfl_xor(ps, 2);
      ps += __shfl_xor(ps, 4);
      ps += __shfl_xor(ps, 8);
      lsum[qq] = lsum[qq] * __expf(m[qq] - nm) + ps;
      m[qq] = nm;
    }
    __syncthreads();
  }

  float invl[8];
#pragma unroll
  for (int qq = 0; qq < 8; ++qq) invl[qq] = 1.0f / lsum[qq];

  // ---------- phase 2: recompute scores, write p once, PV ----------
  float acc[8][4] = {};
  for (int jt = 0; jt < SS / CT; ++jt) {
    int j0 = jt * CT;
    {
      int d4 = ty * 4;
#pragma unroll
      for (int rr = 0; rr < 4; ++rr) {
        int row = tx + 16 * rr;
        float4 kv = *(const float4*)&k[((size_t)bh * SS + j0 + row) * DHH + d4];
        kps[d4+0][row] = kv.x; kps[d4+1][row] = kv.y;
        kps[d4+2][row] = kv.z; kps[d4+3][row] = kv.w;
      }
#pragma unroll
      for (int rr = 0; rr < 4; ++rr) {
        int row = ty + 16 * rr;
        *(float4*)&vs[row][tx * 4] =
            *(const float4*)&v[((size_t)bh * SS + j0 + row) * DHH + tx * 4];
      }
    }
    __syncthreads();

    float sc[8][4] = {};
#pragma unroll 4
    for (int d = 0; d < 64; ++d) {
      float4 a0 = *(const float4*)&qT[d][ty * 8];
      float4 a1 = *(const float4*)&qT[d][ty * 8 + 4];
      float4 kb = *(const float4*)&kps[d][tx * 4];
      float aa[8] = {a0.x, a0.y, a0.z, a0.w, a1.x, a1.y, a1.z, a1.w};
      float bb[4] = {kb.x, kb.y, kb.z, kb.w};
#pragma unroll
      for (int qq = 0; qq < 8; ++qq)
#pragma unroll
        for (int c = 0; c < 4; ++c)
          sc[qq][c] += aa[qq] * bb[c];
    }
    int4 mv = *(const int4*)&mask[b * SS + j0 + tx * 4];
    int mm[4] = {mv.x, mv.y, mv.z, mv.w};
#pragma unroll
    for (int qq = 0; qq < 8; ++qq)
#pragma unroll
      for (int c = 0; c < 4; ++c) {
        float s = sc[qq][c] * scale;
        s = (mm[c] == 0) ? -1e9f : s;
        sc[qq][c] = __expf(s - m[qq]) * invl[qq];
      }
    {
      float* arow = attn_g + ((size_t)bh * SS + i0) * SS + j0;
#pragma unroll
      for (int qq = 0; qq < 8; ++qq) {
        float4 wv = make_float4(sc[qq][0], sc[qq][1], sc[qq][2], sc[qq][3]);
        *(float4*)&arow[(size_t)(ty * 8 + qq) * SS + tx * 4] = wv;
      }
    }
    __syncthreads();
#pragma unroll
    for (int c = 0; c < 4; ++c) {
      float4 w0 = make_float4(sc[0][c], sc[1][c], sc[2][c], sc[3][c]);
      float4 w1 = make_float4(sc[4][c], sc[5][c], sc[6][c], sc[7][c]);
      *(float4*)&kps[tx * 4 + c][ty * 8]     = w0;
      *(float4*)&kps[tx * 4 + c][ty * 8 + 4] = w1;
    }
    __syncthreads();
#pragma unroll 4
    for (int j = 0; j < CT; ++j) {
      float4 pa = *(const float4*)&kps[j][ty * 8];
      float4 pb = *(const float4*)&kps[j][ty * 8 + 4];
      float4 vv = *(const float4*)&vs[j][tx * 4];
      float pp[8] = {pa.x, pa.y, pa.z, pa.w, pb.x, pb.y, pb.z, pb.w};
#pragma unroll
      for (int qq = 0; qq < 8; ++qq) {
        acc[qq][0] += pp[qq] * vv.x;
        acc[qq][1] += pp[qq] * vv.y;
        acc[qq][2] += pp[qq] * vv.z;
        acc[qq][3] += pp[qq] * vv.w;
      }
    }
    __syncthreads();
  }

  // epilogue: emit hi/lo bf16 planes of head-merged output (B,S,D)
#pragma unroll
  for (int qq = 0; qq < 8; ++qq) {
    size_t base = ((size_t)b * SS + i0 + ty * 8 + qq) * DD + h * DHH + tx * 4;
    unsigned short hs[4], ls[4];
#pragma unroll
    for (int j = 0; j < 4; ++j) {
      float f = acc[qq][j];
      hs[j] = f2bf(f);
      ls[j] = f2bf(f - __uint_as_float(((unsigned int)hs[j]) << 16));
    }
    ushort4 H, L;
    H.x = hs[0]; H.y = hs[1]; H.z = hs[2]; H.w = hs[3];
    L.x = ls[0]; L.y = ls[1]; L.z = ls[2]; L.w = ls[3];
    *(ushort4*)&hiO[base] = H;
    *(ushort4*)&loO[base] = L;
  }
}

// ---------------- launch ----------------
extern "C" void kernel_launch(void* const* d_in, const int* in_sizes, int n_in,
                              void* d_out, int out_size, void* d_ws, size_t ws_size,
                              hipStream_t stream) {
  const float* Q   = (const float*)d_in[0];
  const float* K   = (const float*)d_in[1];
  const float* V   = (const float*)d_in[2];
  const int*  mask = (const int*)d_in[3];
  const float* Wq  = (const float*)d_in[4];
  const float* bq  = (const float*)d_in[5];
  const float* Wk  = (const float*)d_in[6];
  const float* bk  = (const float*)d_in[7];
  const float* Wv  = (const float*)d_in[8];
  const float* bv  = (const float*)d_in[9];
  const float* Wo  = (const float*)d_in[10];
  const float* bo  = (const float*)d_in[11];

  float* out    = (float*)d_out;                       // (B,S,D)
  float* attn_g = out + (size_t)NN * DD;               // (B,H,S,S)

  // Pre-attn split planes live in attn_g (dead scratch until attn writes it).
  unsigned short* hiA = (unsigned short*)attn_g;       // NN*DD
  unsigned short* loA = hiA + (size_t)NN * DD;
  unsigned short* hiW = loA + (size_t)NN * DD;         // DD*DD
  unsigned short* loW = hiW + (size_t)DD * DD;

  float* ws = (float*)d_ws;
  float* qh = ws;                                      // (B,H,S,Dh) fp32
  float* kh = qh + (size_t)NN * DD;
  float* vh = kh + (size_t)NN * DD;
  unsigned short* hiO = (unsigned short*)(vh + (size_t)NN * DD);
  unsigned short* loO = hiO + (size_t)NN * DD;
  unsigned short* hiWo = (unsigned short*)qh;
  unsigned short* loWo = hiWo + (size_t)DD * DD;

  const int n4A = NN * DD / 4;   // 1048576
  const int n4W = DD * DD / 4;   // 262144

  dim3 gG(DD / GBN, NN / GBM);   // (8, 32)
  dim3 b256(256);

  // Q projection
  hipLaunchKernelGGL(split_hl, dim3(1024), b256, 0, stream, Wq, hiW, loW, n4W);
  hipLaunchKernelGGL(split_hl, dim3(2048), b256, 0, stream, Q, hiA, loA, n4A);
  hipLaunchKernelGGL(gemm_bf16x3, gG, b256, 0, stream, hiA, loA, hiW, loW, bq, qh, 1);
  // K projection
  hipLaunchKernelGGL(split_hl, dim3(1024), b256, 0, stream, Wk, hiW, loW, n4W);
  hipLaunchKernelGGL(split_hl, dim3(2048), b256, 0, stream, K, hiA, loA, n4A);
  hipLaunchKernelGGL(gemm_bf16x3, gG, b256, 0, stream, hiA, loA, hiW, loW, bk, kh, 1);
  // V projection
  hipLaunchKernelGGL(split_hl, dim3(1024), b256, 0, stream, Wv, hiW, loW, n4W);
  hipLaunchKernelGGL(split_hl, dim3(2048), b256, 0, stream, V, hiA, loA, n4A);
  hipLaunchKernelGGL(gemm_bf16x3, gG, b256, 0, stream, hiA, loA, hiW, loW, bv, vh, 1);

  // attention (overwrites attn_g scratch with the real attn output)
  dim3 gAttn(BB * HH, SS / RB);   // (32, 16)
  hipLaunchKernelGGL(attn_kernel, gAttn, b256, 0, stream,
                     qh, kh, vh, mask, attn_g, hiO, loO);

  // output projection
  hipLaunchKernelGGL(split_hl, dim3(1024), b256, 0, stream, Wo, hiWo, loWo, n4W);
  hipLaunchKernelGGL(gemm_bf16x3, gG, b256, 0, stream, hiO, loO, hiWo, loWo, bo, out, 0);
}

// Round 4
// 1061.920 us; speedup vs baseline: 2.2247x; 1.3460x over previous
//
#include <hip/hip_runtime.h>

// Problem constants
#define BB 2
#define SS 2048
#define DD 1024
#define HH 16
#define DHH 64
#define NN (BB*SS)   // 4096
#define NNDD ((size_t)NN * DD)
#define DDDD ((size_t)DD * DD)

typedef __attribute__((ext_vector_type(8))) __bf16 bf16x8;
typedef __attribute__((ext_vector_type(4))) float f32x4;
typedef union { unsigned int u[4]; bf16x8 v; } bfu8;

__device__ __forceinline__ unsigned short f2bf(float f) {
  unsigned int u = __float_as_uint(f);
  return (unsigned short)((u + 0x7FFFu + ((u >> 16) & 1u)) >> 16);
}
__device__ __forceinline__ float bf2f(unsigned short h) {
  return __uint_as_float(((unsigned int)h) << 16);
}

// global -> LDS direct (16 B per lane). LDS dest wave-uniform; HW writes
// base + lane*16. Global addr per-lane (pre-swizzled source).
__device__ __forceinline__ void gl_lds16(const unsigned short* g, unsigned short* l) {
  __builtin_amdgcn_global_load_lds(
      (const __attribute__((address_space(1))) unsigned int*)g,
      (__attribute__((address_space(3))) unsigned int*)l, 16, 0, 0);
}

#define MFMA16(a, b, c) __builtin_amdgcn_mfma_f32_16x16x32_bf16((a), (b), (c), 0, 0, 0)

// ---------------- split: fp32 -> (hi, lo) bf16 planes, 3 tensors via grid.z --
__global__ __launch_bounds__(256) void split3(
    const float* __restrict__ x0, const float* __restrict__ x1,
    const float* __restrict__ x2, unsigned short* __restrict__ outbase,
    size_t zstride, int n4) {
  const float* x = (blockIdx.z == 0) ? x0 : (blockIdx.z == 1 ? x1 : x2);
  unsigned short* hi = outbase + (size_t)blockIdx.z * zstride;
  unsigned short* lo = hi + (size_t)n4 * 4;
  int i = blockIdx.x * 256 + threadIdx.x;
  int stride = gridDim.x * 256;
  for (; i < n4; i += stride) {
    float4 v = ((const float4*)x)[i];
    float f[4] = {v.x, v.y, v.z, v.w};
    unsigned short hs[4], ls[4];
#pragma unroll
    for (int j = 0; j < 4; ++j) {
      hs[j] = f2bf(f[j]);
      ls[j] = f2bf(f[j] - bf2f(hs[j]));
    }
    ushort4 H, L;
    H.x = hs[0]; H.y = hs[1]; H.z = hs[2]; H.w = hs[3];
    L.x = ls[0]; L.y = ls[1]; L.z = ls[2]; L.w = ls[3];
    ((ushort4*)hi)[i] = H;
    ((ushort4*)lo)[i] = L;
  }
}

// ---------------- GEMM (bf16x3 MFMA): C[m,n] = sum_k A[m,k]*W[n,k] + bias[n] --
// 128x128 tile, BK=64, 4 waves (2x2), wave tile 64x64 = 4x4 frags of 16x16x32.
// Staging: global_load_lds w=16, linear LDS dest, pre-swizzled source chunk.
// grid.z selects (A, W, bias, out). mode 0: fp32 plain store.
// mode 1: head-split store; z<2 -> hi/lo bf16 planes; z==2 -> packed u32.
#define GBM 128
#define GBN 128
#define GBK 64

__global__ __launch_bounds__(256, 2) void gemm_bf16x3(
    const unsigned short* __restrict__ Abase, size_t aZstride,
    const unsigned short* __restrict__ Wbase, size_t wZstride,
    const float* __restrict__ b0, const float* __restrict__ b1,
    const float* __restrict__ b2,
    float* __restrict__ obase, size_t oZstride, int mode) {
  __shared__ __align__(16) unsigned short sAh[GBM * GBK];
  __shared__ __align__(16) unsigned short sAl[GBM * GBK];
  __shared__ __align__(16) unsigned short sBh[GBN * GBK];
  __shared__ __align__(16) unsigned short sBl[GBN * GBK];

  const int z = blockIdx.z;
  const unsigned short* Ah = Abase + (size_t)z * aZstride;
  const unsigned short* Al = Ah + NNDD;
  const unsigned short* Bh = Wbase + (size_t)z * wZstride;
  const unsigned short* Bl = Bh + DDDD;
  const float* bias = (z == 0) ? b0 : (z == 1 ? b1 : b2);
  float* out = obase + (size_t)z * oZstride;

  const int t  = threadIdx.x;
  const int l  = t & 63;
  const int w  = t >> 6;
  const int wr = w >> 1, wc = w & 1;
  const int m0 = blockIdx.y * GBM, n0 = blockIdx.x * GBN;

  const int lrow   = l >> 3;
  const int lchunk = (l & 7) ^ lrow;

  f32x4 acc[4][4] = {};

  const int NT = DD / GBK;  // 16
  for (int kt = 0; kt < NT; ++kt) {
    const int k0 = kt * GBK;
#pragma unroll
    for (int r = 0; r < 4; ++r) {
      int rowb = w * 32 + r * 8;
      size_t gA = (size_t)(m0 + rowb + lrow) * DD + k0 + lchunk * 8;
      size_t gB = (size_t)(n0 + rowb + lrow) * DD + k0 + lchunk * 8;
      int lo = rowb * 64;
      gl_lds16(Ah + gA, sAh + lo);
      gl_lds16(Al + gA, sAl + lo);
      gl_lds16(Bh + gB, sBh + lo);
      gl_lds16(Bl + gB, sBl + lo);
    }
    __syncthreads();

#pragma unroll
    for (int kk = 0; kk < 2; ++kk) {
      bf16x8 ah[4], al[4], bh[4], bl[4];
      const int ks = kk * 4 + (l >> 4);
      const int sw = (ks ^ (l & 7)) << 4;
#pragma unroll
      for (int f = 0; f < 4; ++f) {
        int ra = (wr * 64 + f * 16 + (l & 15)) * 128 + sw;
        int rb = (wc * 64 + f * 16 + (l & 15)) * 128 + sw;
        ah[f] = *(const bf16x8*)((const char*)sAh + ra);
        al[f] = *(const bf16x8*)((const char*)sAl + ra);
        bh[f] = *(const bf16x8*)((const char*)sBh + rb);
        bl[f] = *(const bf16x8*)((const char*)sBl + rb);
      }
#pragma unroll
      for (int fm = 0; fm < 4; ++fm)
#pragma unroll
        for (int fn = 0; fn < 4; ++fn) {
          acc[fm][fn] = MFMA16(ah[fm], bh[fn], acc[fm][fn]);
          acc[fm][fn] = MFMA16(ah[fm], bl[fn], acc[fm][fn]);
          acc[fm][fn] = MFMA16(al[fm], bh[fn], acc[fm][fn]);
        }
    }
    __syncthreads();
  }

  // epilogue: C/D layout col = lane&15, row = (lane>>4)*4 + reg
#pragma unroll
  for (int fn = 0; fn < 4; ++fn) {
    int col = n0 + wc * 64 + fn * 16 + (l & 15);
    float bv = bias[col];
#pragma unroll
    for (int fm = 0; fm < 4; ++fm) {
      int rbase = m0 + wr * 64 + fm * 16 + (l >> 4) * 4;
#pragma unroll
      for (int r = 0; r < 4; ++r) {
        int row = rbase + r;
        float val = acc[fm][fn][r] + bv;
        if (mode == 0) {
          out[(size_t)row * DD + col] = val;
        } else {
          int bb = row >> 11, s2 = row & (SS - 1);
          int hh = col >> 6, dh = col & 63;
          size_t idx = (((size_t)(bb * HH + hh) * SS) + s2) * DHH + dh;
          unsigned short hp = f2bf(val);
          unsigned short lp = f2bf(val - bf2f(hp));
          if (z == 2) {
            ((unsigned int*)out)[idx] = ((unsigned int)hp << 16) | lp;
          } else {
            ((unsigned short*)out)[idx] = hp;
            (((unsigned short*)out) + NNDD)[idx] = lp;
          }
        }
      }
    }
  }
}

// ---------------- Attention (bf16x3 MFMA flash, 2-pass recompute) ----------
// Block: 64 q-rows x 1 bh; 4 waves, wave w owns rows w*16..+15.
// Per 64-key tile: QK^T via MFMA (A=Q rows, B=K rows, identical algebra to
// the verified GEMM), online (m,l) in registers via shfl butterflies.
// Phase 2 recomputes scores, writes final p to attn_g (only score HBM
// traffic), stages p (packed hi/lo u32) and V^T (packed) in LDS, PV via MFMA.
__global__ __launch_bounds__(256, 3) void attn_mfma(
    const unsigned short* __restrict__ qhi, const unsigned short* __restrict__ qlo,
    const unsigned short* __restrict__ khi, const unsigned short* __restrict__ klo,
    const unsigned int* __restrict__ vpk, const int* __restrict__ mask,
    float* __restrict__ attn_g,
    unsigned short* __restrict__ hiO, unsigned short* __restrict__ loO) {
  const int it = blockIdx.x;   // 0..31 q-tile
  const int bh = blockIdx.y;   // 0..31
  const int b  = bh >> 4;
  const int h  = bh & 15;
  const int i0 = it * 64;

  __shared__ __align__(16) unsigned short sQ[2 * 4096];   // Q hi | lo (16 KB)
  __shared__ __align__(16) unsigned int   uKP[64 * 68];   // K planes / P packed
  __shared__ __align__(16) unsigned int   sVT[64 * 68];   // V^T packed

  unsigned short* sQh = sQ;
  unsigned short* sQl = sQ + 4096;
  unsigned short* sKh = (unsigned short*)uKP;
  unsigned short* sKl = sKh + 4096;
  unsigned int*   sP  = uKP;

  const int t  = threadIdx.x;
  const int l  = t & 63;
  const int w  = t >> 6;
  const int lx = l & 15;
  const int ly = l >> 4;

  const int lrow   = l >> 3;
  const int lchunk = (l & 7) ^ lrow;

  // ---- stage Q (once) ----
  {
    size_t gbase = ((size_t)bh * SS + i0) * DHH;
#pragma unroll
    for (int r = 0; r < 2; ++r) {
      int rowb = w * 16 + r * 8;
      size_t g = gbase + (size_t)(rowb + lrow) * DHH + lchunk * 8;
      gl_lds16(qhi + g, sQh + rowb * 64);
      gl_lds16(qlo + g, sQl + rowb * 64);
    }
  }

  float mreg[4], lreg[4];
#pragma unroll
  for (int r = 0; r < 4; ++r) { mreg[r] = -1e30f; lreg[r] = 0.f; }

  const float scale = 0.125f;

  // ---------- phase 1: online (m,l) ----------
  for (int jt = 0; jt < 32; ++jt) {
    const int j0 = jt * 64;
    __syncthreads();
    {
      size_t gbase = ((size_t)bh * SS + j0) * DHH;
#pragma unroll
      for (int r = 0; r < 2; ++r) {
        int rowb = w * 16 + r * 8;
        size_t g = gbase + (size_t)(rowb + lrow) * DHH + lchunk * 8;
        gl_lds16(khi + g, sKh + rowb * 64);
        gl_lds16(klo + g, sKl + rowb * 64);
      }
    }
    __syncthreads();

    f32x4 accS[4] = {};
#pragma unroll
    for (int kk = 0; kk < 2; ++kk) {
      const int cs = ((kk * 4 + ly) ^ (l & 7)) * 8;  // ushort offset
      bf16x8 ah = *(const bf16x8*)(sQh + (w * 16 + lx) * 64 + cs);
      bf16x8 al = *(const bf16x8*)(sQl + (w * 16 + lx) * 64 + cs);
#pragma unroll
      for (int fn = 0; fn < 4; ++fn) {
        bf16x8 kh = *(const bf16x8*)(sKh + (fn * 16 + lx) * 64 + cs);
        bf16x8 kl = *(const bf16x8*)(sKl + (fn * 16 + lx) * 64 + cs);
        accS[fn] = MFMA16(ah, kh, accS[fn]);
        accS[fn] = MFMA16(ah, kl, accS[fn]);
        accS[fn] = MFMA16(al, kh, accS[fn]);
      }
    }

    int mk[4];
#pragma unroll
    for (int fn = 0; fn < 4; ++fn) mk[fn] = mask[b * SS + j0 + fn * 16 + lx];
    float sc[4][4];
#pragma unroll
    for (int fn = 0; fn < 4; ++fn)
#pragma unroll
      for (int r = 0; r < 4; ++r) {
        float s = accS[fn][r] * scale;
        sc[fn][r] = (mk[fn] == 0) ? -1e9f : s;
      }
#pragma unroll
    for (int r = 0; r < 4; ++r) {
      float tm = fmaxf(fmaxf(sc[0][r], sc[1][r]), fmaxf(sc[2][r], sc[3][r]));
      tm = fmaxf(tm, __shfl_xor(tm, 1));
      tm = fmaxf(tm, __shfl_xor(tm, 2));
      tm = fmaxf(tm, __shfl_xor(tm, 4));
      tm = fmaxf(tm, __shfl_xor(tm, 8));
      float nm = fmaxf(mreg[r], tm);
      float ps = __expf(sc[0][r] - nm) + __expf(sc[1][r] - nm) +
                 __expf(sc[2][r] - nm) + __expf(sc[3][r] - nm);
      ps += __shfl_xor(ps, 1);
      ps += __shfl_xor(ps, 2);
      ps += __shfl_xor(ps, 4);
      ps += __shfl_xor(ps, 8);
      lreg[r] = lreg[r] * __expf(mreg[r] - nm) + ps;
      mreg[r] = nm;
    }
  }

  float invl[4];
#pragma unroll
  for (int r = 0; r < 4; ++r) invl[r] = 1.0f / lreg[r];

  // ---------- phase 2: recompute, write p, PV ----------
  f32x4 accO[4] = {};
  for (int jt = 0; jt < 32; ++jt) {
    const int j0 = jt * 64;
    __syncthreads();
    {
      size_t gbase = ((size_t)bh * SS + j0) * DHH;
#pragma unroll
      for (int r = 0; r < 2; ++r) {
        int rowb = w * 16 + r * 8;
        size_t g = gbase + (size_t)(rowb + lrow) * DHH + lchunk * 8;
        gl_lds16(khi + g, sKh + rowb * 64);
        gl_lds16(klo + g, sKl + rowb * 64);
      }
      // stage V^T packed: thread covers 4 rows x one 4-d chunk
#pragma unroll
      for (int rr = 0; rr < 4; ++rr) {
        int j  = rr * 16 + (t >> 4);
        int c4 = t & 15;
        uint4 u = *(const uint4*)&vpk[((size_t)bh * SS + j0 + j) * DHH + c4 * 4];
        sVT[(c4 * 4 + 0) * 68 + j] = u.x;
        sVT[(c4 * 4 + 1) * 68 + j] = u.y;
        sVT[(c4 * 4 + 2) * 68 + j] = u.z;
        sVT[(c4 * 4 + 3) * 68 + j] = u.w;
      }
    }
    __syncthreads();

    f32x4 accS[4] = {};
#pragma unroll
    for (int kk = 0; kk < 2; ++kk) {
      const int cs = ((kk * 4 + ly) ^ (l & 7)) * 8;
      bf16x8 ah = *(const bf16x8*)(sQh + (w * 16 + lx) * 64 + cs);
      bf16x8 al = *(const bf16x8*)(sQl + (w * 16 + lx) * 64 + cs);
#pragma unroll
      for (int fn = 0; fn < 4; ++fn) {
        bf16x8 kh = *(const bf16x8*)(sKh + (fn * 16 + lx) * 64 + cs);
        bf16x8 kl = *(const bf16x8*)(sKl + (fn * 16 + lx) * 64 + cs);
        accS[fn] = MFMA16(ah, kh, accS[fn]);
        accS[fn] = MFMA16(ah, kl, accS[fn]);
        accS[fn] = MFMA16(al, kh, accS[fn]);
      }
    }

    int mk[4];
#pragma unroll
    for (int fn = 0; fn < 4; ++fn) mk[fn] = mask[b * SS + j0 + fn * 16 + lx];
    float p[4][4];
    float* arow = attn_g + ((size_t)bh * SS + i0 + w * 16) * SS + j0;
#pragma unroll
    for (int fn = 0; fn < 4; ++fn)
#pragma unroll
      for (int r = 0; r < 4; ++r) {
        float s = accS[fn][r] * scale;
        s = (mk[fn] == 0) ? -1e9f : s;
        float pv = __expf(s - mreg[r]) * invl[r];
        p[fn][r] = pv;
        arow[(size_t)(ly * 4 + r) * SS + fn * 16 + lx] = pv;
      }
    __syncthreads();   // all waves done reading sK; safe to overwrite with sP

    // pack p -> LDS (own-wave rows only; within-wave ds ordering suffices)
#pragma unroll
    for (int fn = 0; fn < 4; ++fn)
#pragma unroll
      for (int r = 0; r < 4; ++r) {
        unsigned short hp = f2bf(p[fn][r]);
        unsigned short lp = f2bf(p[fn][r] - bf2f(hp));
        sP[(w * 16 + ly * 4 + r) * 68 + fn * 16 + lx] =
            ((unsigned int)hp << 16) | lp;
      }

    // PV: O[m][d] += P[m][j] * V[j][d]
#pragma unroll
    for (int kk = 0; kk < 2; ++kk) {
      const int jb = kk * 32 + ly * 8;
      const unsigned int* pr = &sP[(w * 16 + lx) * 68 + jb];
      uint4 u0 = *(const uint4*)pr;
      uint4 u1 = *(const uint4*)(pr + 4);
      bfu8 pah, pal;
      pah.u[0] = (u0.x >> 16) | (u0.y & 0xFFFF0000u);
      pah.u[1] = (u0.z >> 16) | (u0.w & 0xFFFF0000u);
      pah.u[2] = (u1.x >> 16) | (u1.y & 0xFFFF0000u);
      pah.u[3] = (u1.z >> 16) | (u1.w & 0xFFFF0000u);
      pal.u[0] = (u0.x & 0xFFFFu) | (u0.y << 16);
      pal.u[1] = (u0.z & 0xFFFFu) | (u0.w << 16);
      pal.u[2] = (u1.x & 0xFFFFu) | (u1.y << 16);
      pal.u[3] = (u1.z & 0xFFFFu) | (u1.w << 16);
#pragma unroll
      for (int fn = 0; fn < 4; ++fn) {
        const unsigned int* vr = &sVT[(fn * 16 + lx) * 68 + jb];
        uint4 w0 = *(const uint4*)vr;
        uint4 w1 = *(const uint4*)(vr + 4);
        bfu8 vbh, vbl;
        vbh.u[0] = (w0.x >> 16) | (w0.y & 0xFFFF0000u);
        vbh.u[1] = (w0.z >> 16) | (w0.w & 0xFFFF0000u);
        vbh.u[2] = (w1.x >> 16) | (w1.y & 0xFFFF0000u);
        vbh.u[3] = (w1.z >> 16) | (w1.w & 0xFFFF0000u);
        vbl.u[0] = (w0.x & 0xFFFFu) | (w0.y << 16);
        vbl.u[1] = (w0.z & 0xFFFFu) | (w0.w << 16);
        vbl.u[2] = (w1.x & 0xFFFFu) | (w1.y << 16);
        vbl.u[3] = (w1.z & 0xFFFFu) | (w1.w << 16);
        accO[fn] = MFMA16(pah.v, vbh.v, accO[fn]);
        accO[fn] = MFMA16(pah.v, vbl.v, accO[fn]);
        accO[fn] = MFMA16(pal.v, vbh.v, accO[fn]);
      }
    }
  }

  // epilogue: O rows = i0 + w*16 + ly*4 + r, cols = h*64 + fn*16 + lx
#pragma unroll
  for (int fn = 0; fn < 4; ++fn)
#pragma unroll
    for (int r = 0; r < 4; ++r) {
      float o = accO[fn][r];
      size_t idx = ((size_t)b * SS + i0 + w * 16 + ly * 4 + r) * DD +
                   h * DHH + fn * 16 + lx;
      unsigned short hp = f2bf(o);
      unsigned short lp = f2bf(o - bf2f(hp));
      hiO[idx] = hp;
      loO[idx] = lp;
    }
}

// ---------------- launch ----------------
extern "C" void kernel_launch(void* const* d_in, const int* in_sizes, int n_in,
                              void* d_out, int out_size, void* d_ws, size_t ws_size,
                              hipStream_t stream) {
  const float* Q   = (const float*)d_in[0];
  const float* K   = (const float*)d_in[1];
  const float* V   = (const float*)d_in[2];
  const int*  mask = (const int*)d_in[3];
  const float* Wq  = (const float*)d_in[4];
  const float* bq  = (const float*)d_in[5];
  const float* Wk  = (const float*)d_in[6];
  const float* bk  = (const float*)d_in[7];
  const float* Wv  = (const float*)d_in[8];
  const float* bv  = (const float*)d_in[9];
  const float* Wo  = (const float*)d_in[10];
  const float* bo  = (const float*)d_in[11];

  float* out    = (float*)d_out;                       // (B,S,D)
  float* attn_g = out + NNDD;                          // (B,H,S,S)

  // Pre-attn scratch inside attn_g (dead until attn writes it):
  // input planes [hiQ,loQ | hiK,loK | hiV,loV], then weight planes x3.
  unsigned short* inPlanes = (unsigned short*)attn_g;          // 3 * 2*NNDD
  unsigned short* wPlanes  = inPlanes + 6 * NNDD;              // 3 * 2*DDDD

  float* ws = (float*)d_ws;
  // projection outputs: z-stride NNDD floats each (16 MB)
  //   z0: q planes (hi|lo), z1: k planes, z2: v packed u32
  unsigned short* qhi = (unsigned short*)ws;
  unsigned short* qlo = qhi + NNDD;
  unsigned short* khi = (unsigned short*)(ws + NNDD);
  unsigned short* klo = khi + NNDD;
  unsigned int*   vpk = (unsigned int*)(ws + 2 * NNDD);
  unsigned short* hiO = (unsigned short*)(ws + 3 * NNDD);
  unsigned short* loO = hiO + NNDD;
  // Wo planes reuse the (dead after attn) q-plane region
  unsigned short* woPlanes = (unsigned short*)ws;

  dim3 b256(256);

  // split weights Wq,Wk,Wv and inputs Q,K,V
  hipLaunchKernelGGL(split3, dim3(1024, 1, 3), b256, 0, stream,
                     Wq, Wk, Wv, wPlanes, 2 * DDDD, (int)(DDDD / 4));
  hipLaunchKernelGGL(split3, dim3(2048, 1, 3), b256, 0, stream,
                     Q, K, V, inPlanes, 2 * NNDD, (int)(NNDD / 4));

  // fused QKV projections (grid.z = 3)
  hipLaunchKernelGGL(gemm_bf16x3, dim3(DD / GBN, NN / GBM, 3), b256, 0, stream,
                     inPlanes, 2 * NNDD, wPlanes, 2 * DDDD,
                     bq, bk, bv, ws, NNDD, 1);

  // attention
  hipLaunchKernelGGL(attn_mfma, dim3(32, 32), b256, 0, stream,
                     qhi, qlo, khi, klo, vpk, mask, attn_g, hiO, loO);

  // split Wo (into dead q-plane region), then output projection
  hipLaunchKernelGGL(split3, dim3(1024, 1, 1), b256, 0, stream,
                     Wo, Wo, Wo, woPlanes, 0, (int)(DDDD / 4));
  hipLaunchKernelGGL(gemm_bf16x3, dim3(DD / GBN, NN / GBM, 1), b256, 0, stream,
                     hiO, 0, woPlanes, 0, bo, bo, bo, out, 0, 0);
}

// Round 5
// 1036.991 us; speedup vs baseline: 2.2782x; 1.0240x over previous
//
#include <hip/hip_runtime.h>

// Problem constants
#define BB 2
#define SS 2048
#define DD 1024
#define HH 16
#define DHH 64
#define NN (BB*SS)   // 4096
#define NNDD ((size_t)NN * DD)
#define DDDD ((size_t)DD * DD)

typedef __attribute__((ext_vector_type(8))) __bf16 bf16x8;
typedef __attribute__((ext_vector_type(4))) float f32x4;

__device__ __forceinline__ unsigned short f2bf(float f) {
  unsigned int u = __float_as_uint(f);
  return (unsigned short)((u + 0x7FFFu + ((u >> 16) & 1u)) >> 16);
}
__device__ __forceinline__ float bf2f(unsigned short h) {
  return __uint_as_float(((unsigned int)h) << 16);
}

// global -> LDS direct (16 B/lane). LDS dest wave-uniform (linear);
// per-lane global source carries the inverse swizzle.
__device__ __forceinline__ void gl_lds16(const unsigned short* g, unsigned short* l) {
  __builtin_amdgcn_global_load_lds(
      (const __attribute__((address_space(1))) unsigned int*)g,
      (__attribute__((address_space(3))) unsigned int*)l, 16, 0, 0);
}

#define MFMA16(a, b, c) __builtin_amdgcn_mfma_f32_16x16x32_bf16((a), (b), (c), 0, 0, 0)

// ---------------- split: fp32 -> (hi, lo) bf16 planes, 3 tensors via grid.z --
__global__ __launch_bounds__(256) void split3(
    const float* __restrict__ x0, const float* __restrict__ x1,
    const float* __restrict__ x2, unsigned short* __restrict__ outbase,
    size_t zstride, int n4) {
  const float* x = (blockIdx.z == 0) ? x0 : (blockIdx.z == 1 ? x1 : x2);
  unsigned short* hi = outbase + (size_t)blockIdx.z * zstride;
  unsigned short* lo = hi + (size_t)n4 * 4;
  int i = blockIdx.x * 256 + threadIdx.x;
  int stride = gridDim.x * 256;
  for (; i < n4; i += stride) {
    float4 v = ((const float4*)x)[i];
    float f[4] = {v.x, v.y, v.z, v.w};
    unsigned short hs[4], ls[4];
#pragma unroll
    for (int j = 0; j < 4; ++j) {
      hs[j] = f2bf(f[j]);
      ls[j] = f2bf(f[j] - bf2f(hs[j]));
    }
    ushort4 H, L;
    H.x = hs[0]; H.y = hs[1]; H.z = hs[2]; H.w = hs[3];
    L.x = ls[0]; L.y = ls[1]; L.z = ls[2]; L.w = ls[3];
    ((ushort4*)hi)[i] = H;
    ((ushort4*)lo)[i] = L;
  }
}

// ---------------- V transpose: (B,H,S,Dh) -> (B,H,Dh,S), 2 planes via grid.z --
__global__ __launch_bounds__(256) void vtrans(
    const unsigned short* __restrict__ src, unsigned short* __restrict__ dst) {
  const unsigned short* s = src + (size_t)blockIdx.z * NNDD;
  unsigned short* d = dst + (size_t)blockIdx.z * NNDD;
  const int bh = blockIdx.y;
  const int s0 = blockIdx.x * 64;
  __shared__ unsigned short tile[64][68];
  const int t = threadIdx.x;
#pragma unroll
  for (int r = 0; r < 2; ++r) {
    int idx = t + 256 * r;
    int srow = idx >> 3, c8 = idx & 7;
    const unsigned short* sp = &s[((size_t)bh * SS + s0 + srow) * DHH + c8 * 8];
    ushort4 u0 = *(const ushort4*)sp;
    ushort4 u1 = *(const ushort4*)(sp + 4);
    tile[c8*8+0][srow] = u0.x; tile[c8*8+1][srow] = u0.y;
    tile[c8*8+2][srow] = u0.z; tile[c8*8+3][srow] = u0.w;
    tile[c8*8+4][srow] = u1.x; tile[c8*8+5][srow] = u1.y;
    tile[c8*8+6][srow] = u1.z; tile[c8*8+7][srow] = u1.w;
  }
  __syncthreads();
#pragma unroll
  for (int r = 0; r < 2; ++r) {
    int idx = t + 256 * r;
    int drow = idx >> 3, sc8 = idx & 7;
    ushort4 o0, o1;
    o0.x = tile[drow][sc8*8+0]; o0.y = tile[drow][sc8*8+1];
    o0.z = tile[drow][sc8*8+2]; o0.w = tile[drow][sc8*8+3];
    o1.x = tile[drow][sc8*8+4]; o1.y = tile[drow][sc8*8+5];
    o1.z = tile[drow][sc8*8+6]; o1.w = tile[drow][sc8*8+7];
    unsigned short* dp = &d[((size_t)bh * DHH + drow) * SS + s0 + sc8 * 8];
    *(ushort4*)dp = o0;
    *(ushort4*)(dp + 4) = o1;
  }
}

// ---------------- GEMM (bf16x3 MFMA): C[m,n] = sum_k A[m,k]*W[n,k] + bias[n] --
// 128x128 tile, BK=32, double-buffered LDS (2-phase: prefetch next K-step
// while computing current). 4 waves (2x2), wave tile 64x64 = 4x4 frags.
// XCD-chunked block swizzle for W/A-panel L2 reuse.
#define GBM 128
#define GBN 128
#define GBK 32
#define GNT (DD / GBK)   // 32

__global__ __launch_bounds__(256, 2) void gemm_bf16x3(
    const unsigned short* __restrict__ Abase, size_t aZstride,
    const unsigned short* __restrict__ Wbase, size_t wZstride,
    const float* __restrict__ b0, const float* __restrict__ b1,
    const float* __restrict__ b2,
    float* __restrict__ obase, size_t oZstride, int mode) {
  // [buf][128 rows][32 k] ushort per plane
  __shared__ __align__(16) unsigned short sAh[2 * 4096];
  __shared__ __align__(16) unsigned short sAl[2 * 4096];
  __shared__ __align__(16) unsigned short sBh[2 * 4096];
  __shared__ __align__(16) unsigned short sBl[2 * 4096];

  // bijective XCD-chunked swizzle (nwg % 8 == 0)
  const int gx = gridDim.x, gy = gridDim.y;
  int dlin = blockIdx.x + gx * (blockIdx.y + gy * blockIdx.z);
  int nwg  = gx * gy * gridDim.z;
  int o    = (dlin & 7) * (nwg >> 3) + (dlin >> 3);
  int bx = o % gx; o /= gx;
  int by = o % gy;
  int z  = o / gy;

  const unsigned short* Ah = Abase + (size_t)z * aZstride;
  const unsigned short* Al = Ah + NNDD;
  const unsigned short* Bh = Wbase + (size_t)z * wZstride;
  const unsigned short* Bl = Bh + DDDD;
  const float* bias = (z == 0) ? b0 : (z == 1 ? b1 : b2);
  float* out = obase + (size_t)z * oZstride;

  const int t  = threadIdx.x;
  const int l  = t & 63;
  const int w  = t >> 6;
  const int wr = w >> 1, wc = w & 1;
  const int m0 = by * GBM, n0 = bx * GBN;

  // staging: lane covers (row = rowb + l>>2, chunk (l&3) pre-swizzled)
  const int lrow4  = l >> 2;                       // 0..15
  const int gstage = (lrow4 ^ (lrow4 >> 2)) & 3;
  const int lchunk = (l & 3) ^ gstage;

  f32x4 acc[4][4] = {};

  auto STAGE = [&](int kt, int buf) {
    const int k0 = kt * GBK;
    const int bo = buf * 4096;
#pragma unroll
    for (int r = 0; r < 2; ++r) {
      int rowb = w * 32 + r * 16;                  // wave-uniform
      size_t gA = (size_t)(m0 + rowb + lrow4) * DD + k0 + lchunk * 8;
      size_t gB = (size_t)(n0 + rowb + lrow4) * DD + k0 + lchunk * 8;
      int lo = bo + rowb * 32;
      gl_lds16(Ah + gA, sAh + lo);
      gl_lds16(Al + gA, sAl + lo);
      gl_lds16(Bh + gB, sBh + lo);
      gl_lds16(Bl + gB, sBl + lo);
    }
  };

  const int lx = l & 15, ly = l >> 4;
  const int gread = ((l & 3) ^ ((l >> 2) & 3));    // (row^(row>>2))&3, row%16==lx
  const int cpos  = (ly ^ gread) << 3;             // ushort offset of k-chunk

  auto COMPUTE = [&](int buf) {
    const int bo = buf * 4096;
    bf16x8 ahf[4], alf[4], bhf[4], blf[4];
#pragma unroll
    for (int f = 0; f < 4; ++f) {
      int ra = bo + (wr * 64 + f * 16 + lx) * 32 + cpos;
      int rb = bo + (wc * 64 + f * 16 + lx) * 32 + cpos;
      ahf[f] = *(const bf16x8*)(sAh + ra);
      alf[f] = *(const bf16x8*)(sAl + ra);
      bhf[f] = *(const bf16x8*)(sBh + rb);
      blf[f] = *(const bf16x8*)(sBl + rb);
    }
#pragma unroll
    for (int fm = 0; fm < 4; ++fm)
#pragma unroll
      for (int fn = 0; fn < 4; ++fn) {
        acc[fm][fn] = MFMA16(ahf[fm], bhf[fn], acc[fm][fn]);
        acc[fm][fn] = MFMA16(ahf[fm], blf[fn], acc[fm][fn]);
        acc[fm][fn] = MFMA16(alf[fm], bhf[fn], acc[fm][fn]);
      }
  };

  STAGE(0, 0);
  __syncthreads();
  for (int kt = 0; kt < GNT; ++kt) {
    int cur = kt & 1;
    if (kt + 1 < GNT) STAGE(kt + 1, cur ^ 1);      // in flight across compute
    COMPUTE(cur);
    __syncthreads();                               // drains + publishes next buf
  }

  // epilogue: C/D layout col = lane&15, row = (lane>>4)*4 + reg
#pragma unroll
  for (int fn = 0; fn < 4; ++fn) {
    int col = n0 + wc * 64 + fn * 16 + lx;
    float bv = bias[col];
#pragma unroll
    for (int fm = 0; fm < 4; ++fm) {
      int rbase = m0 + wr * 64 + fm * 16 + ly * 4;
#pragma unroll
      for (int r = 0; r < 4; ++r) {
        int row = rbase + r;
        float val = acc[fm][fn][r] + bv;
        if (mode == 0) {
          out[(size_t)row * DD + col] = val;
        } else {
          int bb = row >> 11, s2 = row & (SS - 1);
          int hh = col >> 6, dh = col & 63;
          size_t idx = (((size_t)(bb * HH + hh) * SS) + s2) * DHH + dh;
          unsigned short hp = f2bf(val);
          ((unsigned short*)out)[idx] = hp;
          (((unsigned short*)out) + NNDD)[idx] = f2bf(val - bf2f(hp));
        }
      }
    }
  }
}

// ---------------- Attention (bf16x3 MFMA flash, 2-pass recompute) ----------
// All operands as separate hi/lo bf16 planes; V pre-transposed (B,H,Dh,S) so
// Q/K/V^T all stage via linear gl_lds16 + chunk-XOR swizzle (no transposes,
// no pack/unpack bitops in the loop). P goes through LDS with the same
// chunk-XOR layout. XCD-chunked swizzle clusters same-bh blocks per XCD.
__global__ __launch_bounds__(256, 3) void attn_mfma(
    const unsigned short* __restrict__ qhi, const unsigned short* __restrict__ qlo,
    const unsigned short* __restrict__ khi, const unsigned short* __restrict__ klo,
    const unsigned short* __restrict__ vthi, const unsigned short* __restrict__ vtlo,
    const int* __restrict__ mask, float* __restrict__ attn_g,
    unsigned short* __restrict__ hiO, unsigned short* __restrict__ loO) {
  int dlin = blockIdx.x + 32 * blockIdx.y;        // 1024 blocks
  int o    = (dlin & 7) * 128 + (dlin >> 3);      // bijective, chunks per XCD
  const int it = o & 31;
  const int bh = o >> 5;
  const int b  = bh >> 4;
  const int h  = bh & 15;
  const int i0 = it * 64;

  __shared__ __align__(16) unsigned short sQh[4096], sQl[4096];   // 16 KB
  __shared__ __align__(16) unsigned short sKP[8192];              // K planes | P planes
  __shared__ __align__(16) unsigned short sVh[4096], sVl[4096];   // 16 KB
  unsigned short* sKh = sKP;
  unsigned short* sKl = sKP + 4096;

  const int t  = threadIdx.x;
  const int l  = t & 63;
  const int w  = t >> 6;
  const int lx = l & 15;
  const int ly = l >> 4;
  const int lrow   = l >> 3;
  const int lchunk = (l & 7) ^ lrow;

  // ---- stage Q (once) ----
  {
    size_t gbase = ((size_t)bh * SS + i0) * DHH;
#pragma unroll
    for (int r = 0; r < 2; ++r) {
      int rowb = w * 16 + r * 8;
      size_t g = gbase + (size_t)(rowb + lrow) * DHH + lchunk * 8;
      gl_lds16(qhi + g, sQh + rowb * 64);
      gl_lds16(qlo + g, sQl + rowb * 64);
    }
  }

  float mreg[4], lreg[4];
#pragma unroll
  for (int r = 0; r < 4; ++r) { mreg[r] = -1e30f; lreg[r] = 0.f; }

  const float scale = 0.125f;

  // ---------- phase 1: online (m,l) ----------
  for (int jt = 0; jt < 32; ++jt) {
    const int j0 = jt * 64;
    __syncthreads();
    {
      size_t gbase = ((size_t)bh * SS + j0) * DHH;
#pragma unroll
      for (int r = 0; r < 2; ++r) {
        int rowb = w * 16 + r * 8;
        size_t g = gbase + (size_t)(rowb + lrow) * DHH + lchunk * 8;
        gl_lds16(khi + g, sKh + rowb * 64);
        gl_lds16(klo + g, sKl + rowb * 64);
      }
    }
    __syncthreads();

    f32x4 accS[4] = {};
#pragma unroll
    for (int kk = 0; kk < 2; ++kk) {
      const int cs = ((kk * 4 + ly) ^ (l & 7)) * 8;
      bf16x8 ah = *(const bf16x8*)(sQh + (w * 16 + lx) * 64 + cs);
      bf16x8 al = *(const bf16x8*)(sQl + (w * 16 + lx) * 64 + cs);
#pragma unroll
      for (int fn = 0; fn < 4; ++fn) {
        bf16x8 kh = *(const bf16x8*)(sKh + (fn * 16 + lx) * 64 + cs);
        bf16x8 kl = *(const bf16x8*)(sKl + (fn * 16 + lx) * 64 + cs);
        accS[fn] = MFMA16(ah, kh, accS[fn]);
        accS[fn] = MFMA16(ah, kl, accS[fn]);
        accS[fn] = MFMA16(al, kh, accS[fn]);
      }
    }

    int mk[4];
#pragma unroll
    for (int fn = 0; fn < 4; ++fn) mk[fn] = mask[b * SS + j0 + fn * 16 + lx];
    float sc[4][4];
#pragma unroll
    for (int fn = 0; fn < 4; ++fn)
#pragma unroll
      for (int r = 0; r < 4; ++r) {
        float s = accS[fn][r] * scale;
        sc[fn][r] = (mk[fn] == 0) ? -1e9f : s;
      }
#pragma unroll
    for (int r = 0; r < 4; ++r) {
      float tm = fmaxf(fmaxf(sc[0][r], sc[1][r]), fmaxf(sc[2][r], sc[3][r]));
      tm = fmaxf(tm, __shfl_xor(tm, 1));
      tm = fmaxf(tm, __shfl_xor(tm, 2));
      tm = fmaxf(tm, __shfl_xor(tm, 4));
      tm = fmaxf(tm, __shfl_xor(tm, 8));
      float nm = fmaxf(mreg[r], tm);
      float ps = __expf(sc[0][r] - nm) + __expf(sc[1][r] - nm) +
                 __expf(sc[2][r] - nm) + __expf(sc[3][r] - nm);
      ps += __shfl_xor(ps, 1);
      ps += __shfl_xor(ps, 2);
      ps += __shfl_xor(ps, 4);
      ps += __shfl_xor(ps, 8);
      lreg[r] = lreg[r] * __expf(mreg[r] - nm) + ps;
      mreg[r] = nm;
    }
  }

  float invl[4];
#pragma unroll
  for (int r = 0; r < 4; ++r) invl[r] = 1.0f / lreg[r];

  // ---------- phase 2: recompute, write p, PV ----------
  f32x4 accO[4] = {};
  for (int jt = 0; jt < 32; ++jt) {
    const int j0 = jt * 64;
    __syncthreads();   // prev-tile P/V readers done
    {
      size_t gbase = ((size_t)bh * SS + j0) * DHH;
#pragma unroll
      for (int r = 0; r < 2; ++r) {
        int rowb = w * 16 + r * 8;
        size_t g  = gbase + (size_t)(rowb + lrow) * DHH + lchunk * 8;
        size_t gv = ((size_t)bh * DHH + rowb + lrow) * SS + j0 + lchunk * 8;
        gl_lds16(khi + g, sKh + rowb * 64);
        gl_lds16(klo + g, sKl + rowb * 64);
        gl_lds16(vthi + gv, sVh + rowb * 64);
        gl_lds16(vtlo + gv, sVl + rowb * 64);
      }
    }
    __syncthreads();

    f32x4 accS[4] = {};
#pragma unroll
    for (int kk = 0; kk < 2; ++kk) {
      const int cs = ((kk * 4 + ly) ^ (l & 7)) * 8;
      bf16x8 ah = *(const bf16x8*)(sQh + (w * 16 + lx) * 64 + cs);
      bf16x8 al = *(const bf16x8*)(sQl + (w * 16 + lx) * 64 + cs);
#pragma unroll
      for (int fn = 0; fn < 4; ++fn) {
        bf16x8 kh = *(const bf16x8*)(sKh + (fn * 16 + lx) * 64 + cs);
        bf16x8 kl = *(const bf16x8*)(sKl + (fn * 16 + lx) * 64 + cs);
        accS[fn] = MFMA16(ah, kh, accS[fn]);
        accS[fn] = MFMA16(ah, kl, accS[fn]);
        accS[fn] = MFMA16(al, kh, accS[fn]);
      }
    }

    int mk[4];
#pragma unroll
    for (int fn = 0; fn < 4; ++fn) mk[fn] = mask[b * SS + j0 + fn * 16 + lx];
    float p[4][4];
    float* arow = attn_g + ((size_t)bh * SS + i0 + w * 16) * SS + j0;
#pragma unroll
    for (int fn = 0; fn < 4; ++fn)
#pragma unroll
      for (int r = 0; r < 4; ++r) {
        float s = accS[fn][r] * scale;
        s = (mk[fn] == 0) ? -1e9f : s;
        float pv = __expf(s - mreg[r]) * invl[r];
        p[fn][r] = pv;
        arow[(size_t)(ly * 4 + r) * SS + fn * 16 + lx] = pv;
      }
    __syncthreads();   // all waves done reading sK; safe to overwrite with P

    // write P planes into sKP, chunk-XOR swizzled (read form == K reads)
#pragma unroll
    for (int fn = 0; fn < 4; ++fn)
#pragma unroll
      for (int r = 0; r < 4; ++r) {
        int prow = w * 16 + ly * 4 + r;
        int pcol = fn * 16 + lx;
        int pos  = (((pcol >> 3) ^ (prow & 7)) << 3) + (pcol & 7);
        unsigned short hp = f2bf(p[fn][r]);
        sKP[prow * 64 + pos] = hp;
        sKP[4096 + prow * 64 + pos] = f2bf(p[fn][r] - bf2f(hp));
      }

    // PV: O[m][d] += P[m][j] * V^T[d][j]  (own-wave P rows; same-wave ds order)
#pragma unroll
    for (int kk = 0; kk < 2; ++kk) {
      const int cs = ((kk * 4 + ly) ^ (l & 7)) * 8;
      bf16x8 pah = *(const bf16x8*)(sKP + (w * 16 + lx) * 64 + cs);
      bf16x8 pal = *(const bf16x8*)(sKP + 4096 + (w * 16 + lx) * 64 + cs);
#pragma unroll
      for (int fn = 0; fn < 4; ++fn) {
        bf16x8 vbh = *(const bf16x8*)(sVh + (fn * 16 + lx) * 64 + cs);
        bf16x8 vbl = *(const bf16x8*)(sVl + (fn * 16 + lx) * 64 + cs);
        accO[fn] = MFMA16(pah, vbh, accO[fn]);
        accO[fn] = MFMA16(pah, vbl, accO[fn]);
        accO[fn] = MFMA16(pal, vbh, accO[fn]);
      }
    }
  }

  // epilogue: O rows = i0 + w*16 + ly*4 + r, cols = h*64 + fn*16 + lx
#pragma unroll
  for (int fn = 0; fn < 4; ++fn)
#pragma unroll
    for (int r = 0; r < 4; ++r) {
      float ov = accO[fn][r];
      size_t idx = ((size_t)b * SS + i0 + w * 16 + ly * 4 + r) * DD +
                   h * DHH + fn * 16 + lx;
      unsigned short hp = f2bf(ov);
      hiO[idx] = hp;
      loO[idx] = f2bf(ov - bf2f(hp));
    }
}

// ---------------- launch ----------------
extern "C" void kernel_launch(void* const* d_in, const int* in_sizes, int n_in,
                              void* d_out, int out_size, void* d_ws, size_t ws_size,
                              hipStream_t stream) {
  const float* Q   = (const float*)d_in[0];
  const float* K   = (const float*)d_in[1];
  const float* V   = (const float*)d_in[2];
  const int*  mask = (const int*)d_in[3];
  const float* Wq  = (const float*)d_in[4];
  const float* bq  = (const float*)d_in[5];
  const float* Wk  = (const float*)d_in[6];
  const float* bk  = (const float*)d_in[7];
  const float* Wv  = (const float*)d_in[8];
  const float* bv  = (const float*)d_in[9];
  const float* Wo  = (const float*)d_in[10];
  const float* bo  = (const float*)d_in[11];

  float* out    = (float*)d_out;                       // (B,S,D)
  float* attn_g = out + NNDD;                          // (B,H,S,S)

  // Pre-attn scratch inside attn_g (dead until attn writes it)
  unsigned short* inPlanes = (unsigned short*)attn_g;  // 3 * 2*NNDD ushort
  unsigned short* wPlanes  = inPlanes + 6 * NNDD;      // 3 * 2*DDDD ushort

  float* ws = (float*)d_ws;
  // slots of NNDD floats (= 2*NNDD ushorts) each:
  unsigned short* qPl  = (unsigned short*)ws;              // slot0: q hi|lo
  unsigned short* kPl  = (unsigned short*)(ws + NNDD);     // slot1: k hi|lo
  unsigned short* vPl  = (unsigned short*)(ws + 2 * NNDD); // slot2: v hi|lo -> later O hi|lo
  unsigned short* vtPl = (unsigned short*)(ws + 3 * NNDD); // slot3: V^T hi|lo

  dim3 b256(256);

  // splits
  hipLaunchKernelGGL(split3, dim3(1024, 1, 3), b256, 0, stream,
                     Wq, Wk, Wv, wPlanes, 2 * DDDD, (int)(DDDD / 4));
  hipLaunchKernelGGL(split3, dim3(2048, 1, 3), b256, 0, stream,
                     Q, K, V, inPlanes, 2 * NNDD, (int)(NNDD / 4));

  // fused QKV projections -> plane pairs in slots 0,1,2 (head-split layout)
  hipLaunchKernelGGL(gemm_bf16x3, dim3(DD / GBN, NN / GBM, 3), b256, 0, stream,
                     inPlanes, 2 * NNDD, wPlanes, 2 * DDDD,
                     bq, bk, bv, ws, NNDD, 1);

  // V transpose: slot2 (B,H,S,Dh) -> slot3 (B,H,Dh,S), both planes
  hipLaunchKernelGGL(vtrans, dim3(SS / 64, BB * HH, 2), b256, 0, stream,
                     vPl, vtPl);

  // attention: writes attn_g + O planes into slot2 (row-major V dead)
  hipLaunchKernelGGL(attn_mfma, dim3(32, 32), b256, 0, stream,
                     qPl, qPl + NNDD, kPl, kPl + NNDD, vtPl, vtPl + NNDD,
                     mask, attn_g, vPl, vPl + NNDD);

  // split Wo into slot0 (dead after attn), then output projection
  hipLaunchKernelGGL(split3, dim3(1024, 1, 1), b256, 0, stream,
                     Wo, Wo, Wo, qPl, 0, (int)(DDDD / 4));
  hipLaunchKernelGGL(gemm_bf16x3, dim3(DD / GBN, NN / GBM, 1), b256, 0, stream,
                     vPl, 0, qPl, 0, bo, bo, bo, out, 0, 0);
}